// Round 1
// baseline (277.216 us; speedup 1.0000x reference)
//
#include <hip/hip_runtime.h>
#include <cstdint>
#include <cstddef>

#define SLEN 2048
#define NB 2
#define NH 32
#define NKV 8
#define HD 64
#define MROWS 4096   // NB*SLEN
#define QDIM 2048    // NH*HD
#define KVDIM 512    // NKV*HD
#define WINH 256     // WIN/2

typedef float f32x4 __attribute__((ext_vector_type(4)));
typedef __bf16 bf16x8 __attribute__((ext_vector_type(8)));

__device__ __forceinline__ unsigned short f2bf(float f) {
  union { float f; unsigned u; } v; v.f = f;
  unsigned r = v.u + 0x7fffu + ((v.u >> 16) & 1u);
  return (unsigned short)(r >> 16);
}
__device__ __forceinline__ float bf2f(unsigned short h) {
  union { unsigned u; float f; } v; v.u = ((unsigned)h) << 16;
  return v.f;
}
__device__ __forceinline__ unsigned pk2(float a, float b) {
  return (unsigned)f2bf(a) | ((unsigned)f2bf(b) << 16);
}
__device__ __forceinline__ uint4 cvt16(float4 a, float4 b) {
  uint4 u;
  u.x = pk2(a.x, a.y); u.y = pk2(a.z, a.w);
  u.z = pk2(b.x, b.y); u.w = pk2(b.z, b.w);
  return u;
}

// ---------------- RoPE tables: cos/sin[s][d] for d in 0..31 ----------------
__global__ void rope_table(float* __restrict__ tc, float* __restrict__ ts) {
  int tid = blockIdx.x * 256 + threadIdx.x;      // 2048*32 = 65536
  int d = tid & 31;
  int s = tid >> 5;
  // inv_freq = 10000^(-2d/64) = exp(-(2d/64)*ln(10000))
  float inv = expf((float)d * (-2.0f / 64.0f) * 9.210340371976184f);
  float ang = (float)s * inv;
  float sn, cs;
  sincosf(ang, &sn, &cs);
  tc[tid] = cs;
  ts[tid] = sn;
}

// ---------------- QKV GEMM: C[4096][3072] = x @ [wq;wk;wv]^T, bf16 out ------
__global__ __launch_bounds__(256) void qkv_gemm(
    const float* __restrict__ x, const float* __restrict__ wq,
    const float* __restrict__ wk, const float* __restrict__ wv,
    unsigned short* __restrict__ qb, unsigned short* __restrict__ kb,
    unsigned short* __restrict__ vb)
{
  constexpr int LDK = 40;  // padded stride (bf16 elems) to spread LDS banks
  __shared__ __align__(16) unsigned short As[128 * LDK];
  __shared__ __align__(16) unsigned short Bs[128 * LDK];
  const int m0 = blockIdx.x * 128;
  const int n0 = blockIdx.y * 128;
  const float* W; unsigned short* outp; int nrel, ostride;
  if (n0 < QDIM)              { W = wq; nrel = n0;            outp = qb; ostride = QDIM;  }
  else if (n0 < QDIM + KVDIM) { W = wk; nrel = n0 - QDIM;     outp = kb; ostride = KVDIM; }
  else                        { W = wv; nrel = n0 - QDIM - KVDIM; outp = vb; ostride = KVDIM; }

  const int tid = threadIdx.x;
  const int sr = tid >> 1, sc = (tid & 1) * 16;
  const int lane = tid & 63, wid = tid >> 6;
  const int g = lane >> 4, cl = lane & 15;
  const int wr = (wid >> 1) * 64, wc = (wid & 1) * 64;

  f32x4 acc[4][4] = {};
  const float* ap = x + (size_t)(m0 + sr) * 2048 + sc;
  const float* bp = W + (size_t)(nrel + sr) * 2048 + sc;

  for (int k0 = 0; k0 < 2048; k0 += 32) {
    float4 a0 = *(const float4*)(ap + k0);
    float4 a1 = *(const float4*)(ap + k0 + 4);
    float4 a2 = *(const float4*)(ap + k0 + 8);
    float4 a3 = *(const float4*)(ap + k0 + 12);
    float4 b0 = *(const float4*)(bp + k0);
    float4 b1 = *(const float4*)(bp + k0 + 4);
    float4 b2 = *(const float4*)(bp + k0 + 8);
    float4 b3 = *(const float4*)(bp + k0 + 12);
    __syncthreads();   // previous iter's LDS reads done before overwrite
    *(uint4*)&As[sr * LDK + sc]     = cvt16(a0, a1);
    *(uint4*)&As[sr * LDK + sc + 8] = cvt16(a2, a3);
    *(uint4*)&Bs[sr * LDK + sc]     = cvt16(b0, b1);
    *(uint4*)&Bs[sr * LDK + sc + 8] = cvt16(b2, b3);
    __syncthreads();
    bf16x8 af[4], bf[4];
#pragma unroll
    for (int m = 0; m < 4; ++m)
      af[m] = *(const bf16x8*)&As[(wr + m * 16 + cl) * LDK + g * 8];
#pragma unroll
    for (int n = 0; n < 4; ++n)
      bf[n] = *(const bf16x8*)&Bs[(wc + n * 16 + cl) * LDK + g * 8];
#pragma unroll
    for (int m = 0; m < 4; ++m)
#pragma unroll
      for (int n = 0; n < 4; ++n)
        acc[m][n] = __builtin_amdgcn_mfma_f32_16x16x32_bf16(af[m], bf[n], acc[m][n], 0, 0, 0);
  }
#pragma unroll
  for (int m = 0; m < 4; ++m)
#pragma unroll
    for (int n = 0; n < 4; ++n)
#pragma unroll
      for (int p = 0; p < 4; ++p) {
        int row = m0 + wr + m * 16 + g * 4 + p;
        int col = nrel + wc + n * 16 + cl;
        outp[(size_t)row * ostride + col] = f2bf(acc[m][n][p]);
      }
}

// ---------------- RoPE in-place on q and k (bf16) --------------------------
__global__ void rope_qk(unsigned short* __restrict__ qb,
                        unsigned short* __restrict__ kb,
                        const float* __restrict__ tc, const float* __restrict__ ts) {
  int tid = blockIdx.x * 256 + threadIdx.x;  // 4096*40*32 = 5,242,880
  int d = tid & 31;
  int head = (tid >> 5) % 40;
  int row = tid / 1280;
  int s = row & (SLEN - 1);
  float cs = tc[s * 32 + d], sn = ts[s * 32 + d];
  unsigned short* p = (head < NH)
      ? qb + (size_t)row * QDIM + head * HD
      : kb + (size_t)row * KVDIM + (head - NH) * HD;
  float a = bf2f(p[d]);
  float b = bf2f(p[d + 32]);
  p[d]      = f2bf(a * cs - b * sn);
  p[d + 32] = f2bf(b * cs + a * sn);
}

// ---------------- V transpose: vt[b][kvh][d][s] = vb[b][s][kvh*64+d] -------
__global__ void transpose_v(const unsigned short* __restrict__ vb,
                            unsigned short* __restrict__ vt) {
  int tid = blockIdx.x * 256 + threadIdx.x;  // 2*8*64*2048 = 2,097,152
  int s = tid & (SLEN - 1);
  int d = (tid >> 11) & 63;
  int kvh = (tid >> 17) & 7;
  int b = tid >> 20;
  vt[tid] = vb[((size_t)(b * SLEN + s)) * KVDIM + kvh * HD + d];
}

// ---------------- Flash attention, sliding window --------------------------
// 1 wave = 16 query rows of one (b,h). Swapped QK^T: mfma(K,Q) -> lane holds
// scores for query (lane&15), keys vary. KVBLK=32 per iteration.
__global__ __launch_bounds__(256) void attn(
    const unsigned short* __restrict__ qb, const unsigned short* __restrict__ kb,
    const unsigned short* __restrict__ vt, unsigned short* __restrict__ ao)
{
  __shared__ __align__(16) unsigned short Plds[4][16][40];
  const int lane = threadIdx.x & 63, wid = threadIdx.x >> 6;
  const int g = lane >> 4, cl = lane & 15;
  const int qt = blockIdx.x * 4 + wid;         // 0..8191
  const int bh = qt >> 7, tl = qt & 127;
  const int i0 = tl * 16;
  const int b = bh >> 5, h = bh & 31, kvh = (bh & 31) >> 2;
  const int qi = i0 + cl;

  // Q B-fragments (col = query = cl, k = d)
  const unsigned short* qp = qb + ((size_t)(b * SLEN + i0 + cl) * NH + h) * HD + g * 8;
  bf16x8 qf0 = *(const bf16x8*)qp;
  bf16x8 qf1 = *(const bf16x8*)(qp + 32);

  f32x4 acc_o[4] = {};
  float m_run = -1e30f, l_run = 0.f;
  int jb = i0 - WINH; if (jb < 0) jb = 0;

  for (int j0 = jb; j0 <= i0; j0 += 32) {
    f32x4 sacc[2];
#pragma unroll
    for (int t = 0; t < 2; ++t) {
      int krow = j0 + 16 * t + cl;
      if (krow > SLEN - 1) krow = SLEN - 1;   // masked anyway
      const unsigned short* kp = kb + ((size_t)(b * SLEN + krow) * NKV + kvh) * HD + g * 8;
      bf16x8 kf0 = *(const bf16x8*)kp;
      bf16x8 kf1 = *(const bf16x8*)(kp + 32);
      f32x4 z = {};
      z = __builtin_amdgcn_mfma_f32_16x16x32_bf16(kf0, qf0, z, 0, 0, 0);
      z = __builtin_amdgcn_mfma_f32_16x16x32_bf16(kf1, qf1, z, 0, 0, 0);
      sacc[t] = z;
    }
    // mask + scale; row (=query) max over 32 keys
    float s[2][4];
    float mx = -1e30f;
#pragma unroll
    for (int t = 0; t < 2; ++t)
#pragma unroll
      for (int p = 0; p < 4; ++p) {
        int kj = j0 + 16 * t + g * 4 + p;
        bool ok = (kj <= qi) && (qi - kj <= WINH);
        float v = ok ? sacc[t][p] * 0.125f : -1e30f;
        s[t][p] = v;
        mx = fmaxf(mx, v);
      }
    mx = fmaxf(mx, __shfl_xor(mx, 16));
    mx = fmaxf(mx, __shfl_xor(mx, 32));
    float mnew = fmaxf(m_run, mx);
    float corr = __expf(m_run - mnew);
    float ps = 0.f;
    unsigned pw[2][2];
#pragma unroll
    for (int t = 0; t < 2; ++t) {
      float p0 = __expf(s[t][0] - mnew);
      float p1 = __expf(s[t][1] - mnew);
      float p2 = __expf(s[t][2] - mnew);
      float p3 = __expf(s[t][3] - mnew);
      ps += p0 + p1 + p2 + p3;
      pw[t][0] = pk2(p0, p1);
      pw[t][1] = pk2(p2, p3);
    }
    ps += __shfl_xor(ps, 16);
    ps += __shfl_xor(ps, 32);
    l_run = l_run * corr + ps;
    m_run = mnew;
#pragma unroll
    for (int vbk = 0; vbk < 4; ++vbk)
#pragma unroll
      for (int p = 0; p < 4; ++p) acc_o[vbk][p] *= corr;
    // P -> LDS transposed [query][key] (bf16), then B-frag read
#pragma unroll
    for (int t = 0; t < 2; ++t) {
      *(unsigned*)&Plds[wid][cl][16 * t + 4 * g]     = pw[t][0];
      *(unsigned*)&Plds[wid][cl][16 * t + 4 * g + 2] = pw[t][1];
    }
    bf16x8 pf = *(const bf16x8*)&Plds[wid][cl][g * 8];
    // V^T A-fragments (row = d_local = cl, k = key), PV accumulate
    int jv = j0 + g * 8;
    if (jv > SLEN - 8) jv = SLEN - 8;          // masked keys -> p = 0
    const unsigned short* vbase = vt + ((size_t)(b * NKV + kvh) * HD) * SLEN + jv;
#pragma unroll
    for (int vbk = 0; vbk < 4; ++vbk) {
      bf16x8 vf = *(const bf16x8*)(vbase + (size_t)(vbk * 16 + cl) * SLEN);
      acc_o[vbk] = __builtin_amdgcn_mfma_f32_16x16x32_bf16(vf, pf, acc_o[vbk], 0, 0, 0);
    }
  }
  float inv = 1.0f / l_run;
  unsigned short* op = ao + ((size_t)(b * SLEN + i0 + cl) * NH + h) * HD;
#pragma unroll
  for (int vbk = 0; vbk < 4; ++vbk) {
    unsigned u0 = pk2(acc_o[vbk][0] * inv, acc_o[vbk][1] * inv);
    unsigned u1 = pk2(acc_o[vbk][2] * inv, acc_o[vbk][3] * inv);
    *(unsigned*)(op + vbk * 16 + g * 4)     = u0;
    *(unsigned*)(op + vbk * 16 + g * 4 + 2) = u1;
  }
}

// ---------------- Output GEMM: out[4096][2048] = ao @ wo^T (fp32 out) ------
__global__ __launch_bounds__(256) void out_gemm(
    const unsigned short* __restrict__ ao, const float* __restrict__ wo,
    float* __restrict__ out)
{
  constexpr int LDK = 40;
  __shared__ __align__(16) unsigned short As[128 * LDK];
  __shared__ __align__(16) unsigned short Bs[128 * LDK];
  const int m0 = blockIdx.x * 128;
  const int n0 = blockIdx.y * 128;
  const int tid = threadIdx.x;
  const int sr = tid >> 1, sc = (tid & 1) * 16;
  const int lane = tid & 63, wid = tid >> 6;
  const int g = lane >> 4, cl = lane & 15;
  const int wr = (wid >> 1) * 64, wc = (wid & 1) * 64;

  f32x4 acc[4][4] = {};
  const unsigned short* ap = ao + (size_t)(m0 + sr) * 2048 + sc;
  const float* bp = wo + (size_t)(n0 + sr) * 2048 + sc;

  for (int k0 = 0; k0 < 2048; k0 += 32) {
    uint4 va0 = *(const uint4*)(ap + k0);
    uint4 va1 = *(const uint4*)(ap + k0 + 8);
    float4 b0 = *(const float4*)(bp + k0);
    float4 b1 = *(const float4*)(bp + k0 + 4);
    float4 b2 = *(const float4*)(bp + k0 + 8);
    float4 b3 = *(const float4*)(bp + k0 + 12);
    __syncthreads();
    *(uint4*)&As[sr * LDK + sc]     = va0;
    *(uint4*)&As[sr * LDK + sc + 8] = va1;
    *(uint4*)&Bs[sr * LDK + sc]     = cvt16(b0, b1);
    *(uint4*)&Bs[sr * LDK + sc + 8] = cvt16(b2, b3);
    __syncthreads();
    bf16x8 af[4], bf[4];
#pragma unroll
    for (int m = 0; m < 4; ++m)
      af[m] = *(const bf16x8*)&As[(wr + m * 16 + cl) * LDK + g * 8];
#pragma unroll
    for (int n = 0; n < 4; ++n)
      bf[n] = *(const bf16x8*)&Bs[(wc + n * 16 + cl) * LDK + g * 8];
#pragma unroll
    for (int m = 0; m < 4; ++m)
#pragma unroll
      for (int n = 0; n < 4; ++n)
        acc[m][n] = __builtin_amdgcn_mfma_f32_16x16x32_bf16(af[m], bf[n], acc[m][n], 0, 0, 0);
  }
#pragma unroll
  for (int m = 0; m < 4; ++m)
#pragma unroll
    for (int n = 0; n < 4; ++n)
#pragma unroll
      for (int p = 0; p < 4; ++p) {
        int row = m0 + wr + m * 16 + g * 4 + p;
        int col = n0 + wc + n * 16 + cl;
        out[(size_t)row * 2048 + col] = acc[m][n][p];
      }
}

// ---------------- launch ---------------------------------------------------
extern "C" void kernel_launch(void* const* d_in, const int* in_sizes, int n_in,
                              void* d_out, int out_size, void* d_ws, size_t ws_size,
                              hipStream_t stream) {
  const float* x  = (const float*)d_in[0];
  const float* wq = (const float*)d_in[1];
  const float* wk = (const float*)d_in[2];
  const float* wv = (const float*)d_in[3];
  const float* wo = (const float*)d_in[4];
  float* out = (float*)d_out;

  char* w = (char*)d_ws;
  unsigned short* qb = (unsigned short*)w; w += (size_t)MROWS * QDIM * 2;   // 16 MB
  unsigned short* kb = (unsigned short*)w; w += (size_t)MROWS * KVDIM * 2;  // 4 MB
  unsigned short* vb = (unsigned short*)w; w += (size_t)MROWS * KVDIM * 2;  // 4 MB
  unsigned short* vt = (unsigned short*)w; w += (size_t)MROWS * KVDIM * 2;  // 4 MB
  unsigned short* ao = (unsigned short*)w; w += (size_t)MROWS * QDIM * 2;   // 16 MB
  float* tabc = (float*)w; w += (size_t)SLEN * 32 * 4;
  float* tabs = (float*)w; w += (size_t)SLEN * 32 * 4;

  rope_table<<<SLEN * 32 / 256, 256, 0, stream>>>(tabc, tabs);
  qkv_gemm<<<dim3(MROWS / 128, (QDIM + 2 * KVDIM) / 128), 256, 0, stream>>>(
      x, wq, wk, wv, qb, kb, vb);
  rope_qk<<<(MROWS * 40 * 32) / 256, 256, 0, stream>>>(qb, kb, tabc, tabs);
  transpose_v<<<(MROWS * KVDIM) / 256, 256, 0, stream>>>(vb, vt);
  attn<<<(NB * NH * (SLEN / 16)) / 4, 256, 0, stream>>>(qb, kb, vt, ao);
  out_gemm<<<dim3(MROWS / 128, QDIM / 128), 256, 0, stream>>>(ao, wo, out);
}

// Round 2
// 228.574 us; speedup vs baseline: 1.2128x; 1.2128x over previous
//
#include <hip/hip_runtime.h>
#include <cstdint>
#include <cstddef>

#define SLEN 2048
#define NB 2
#define NH 32
#define NKV 8
#define HD 64
#define MROWS 4096   // NB*SLEN
#define QDIM 2048    // NH*HD
#define KVDIM 512    // NKV*HD
#define WINH 256     // WIN/2

typedef float f32x4 __attribute__((ext_vector_type(4)));
typedef __bf16 bf16x8 __attribute__((ext_vector_type(8)));

__device__ __forceinline__ unsigned short f2bf(float f) {
  union { float f; unsigned u; } v; v.f = f;
  unsigned r = v.u + 0x7fffu + ((v.u >> 16) & 1u);
  return (unsigned short)(r >> 16);
}
__device__ __forceinline__ float bf2f(unsigned short h) {
  union { unsigned u; float f; } v; v.u = ((unsigned)h) << 16;
  return v.f;
}
__device__ __forceinline__ unsigned pk2(float a, float b) {
  return (unsigned)f2bf(a) | ((unsigned)f2bf(b) << 16);
}
__device__ __forceinline__ uint4 cvt16(float4 a, float4 b) {
  uint4 u;
  u.x = pk2(a.x, a.y); u.y = pk2(a.z, a.w);
  u.z = pk2(b.x, b.y); u.w = pk2(b.z, b.w);
  return u;
}
// async global->LDS, 16B per lane; LDS dest must be wave-uniform base
__device__ __forceinline__ void async16(const unsigned short* g, unsigned short* l) {
  __builtin_amdgcn_global_load_lds(
      (const __attribute__((address_space(1))) unsigned int*)g,
      (__attribute__((address_space(3))) unsigned int*)l, 16, 0, 0);
}

// ---------------- RoPE table: tab[s*32+d] = {cos, sin} ---------------------
__global__ void rope_table(float2* __restrict__ tab) {
  int tid = blockIdx.x * 256 + threadIdx.x;      // 2048*32 = 65536
  int d = tid & 31;
  int s = tid >> 5;
  float inv = expf((float)d * (-2.0f / 64.0f) * 9.210340371976184f);
  float ang = (float)s * inv;
  float sn, cs;
  sincosf(ang, &sn, &cs);
  tab[tid] = make_float2(cs, sn);
}

// ---------------- fp32 -> bf16 converters ----------------------------------
__global__ void conv_bf16(const float* __restrict__ src, unsigned short* __restrict__ dst) {
  size_t t = (size_t)blockIdx.x * 256 + threadIdx.x;
  float4 a = *(const float4*)(src + t * 8);
  float4 b = *(const float4*)(src + t * 8 + 4);
  *(uint4*)(dst + t * 8) = cvt16(a, b);
}

__global__ void conv_wqkv(const float* __restrict__ wq, const float* __restrict__ wk,
                          const float* __restrict__ wv, unsigned short* __restrict__ dst) {
  size_t t = (size_t)blockIdx.x * 256 + threadIdx.x;   // 786432 threads
  size_t e = t * 8;
  int row = (int)(e >> 11);
  const float* src; size_t off;
  if (row < 2048)       { src = wq; off = e; }
  else if (row < 2560)  { src = wk; off = e - (size_t)2048 * 2048; }
  else                  { src = wv; off = e - (size_t)2560 * 2048; }
  float4 a = *(const float4*)(src + off);
  float4 b = *(const float4*)(src + off + 4);
  *(uint4*)(dst + e) = cvt16(a, b);
}

// ---------------- QKV GEMM (m97 structure) + fused RoPE / V-transpose ------
// C[4096][3072] = xb @ wqkvb^T, all bf16 in, bf16 out split to qb/kb/vt.
__global__ __launch_bounds__(256) void qkv_gemm(
    const unsigned short* __restrict__ xb, const unsigned short* __restrict__ wqkvb,
    const float* __restrict__ tabf,
    unsigned short* __restrict__ qb, unsigned short* __restrict__ kb,
    unsigned short* __restrict__ vt)
{
  __shared__ __align__(16) unsigned short As[128 * 32];
  __shared__ __align__(16) unsigned short Bs[128 * 32];
  const float2* tab = (const float2*)tabf;
  const int m0 = blockIdx.x * 128;
  const int n0 = blockIdx.y * 128;
  const int tid = threadIdx.x;
  const int lane = tid & 63, wid = tid >> 6;
  const int g = lane >> 4, cl = lane & 15;
  const int wr = (wid >> 1) * 64, wc = (wid & 1) * 64;

  // staging: wave wid loads rows [wid*32, wid*32+32), 2 insts x 16 rows
  const int srow = wid * 32 + (lane >> 2);
  const int scol = (lane & 3) * 8;
  const unsigned short* ga = xb + (size_t)(m0 + srow) * 2048 + scol;
  const unsigned short* gb = wqkvb + (size_t)(n0 + srow) * 2048 + scol;
  unsigned short* lA = &As[wid * 1024];   // wave-uniform
  unsigned short* lB = &Bs[wid * 1024];

  f32x4 acc[4][4] = {};
  for (int k0 = 0; k0 < 2048; k0 += 32) {
    async16(ga + k0, lA);
    async16(ga + k0 + (size_t)16 * 2048, lA + 512);
    async16(gb + k0, lB);
    async16(gb + k0 + (size_t)16 * 2048, lB + 512);
    __syncthreads();            // drains vmcnt(0): staging complete
    bf16x8 af[4], bfv[4];
#pragma unroll
    for (int m = 0; m < 4; ++m)
      af[m] = *(const bf16x8*)&As[(wr + m * 16 + cl) * 32 + g * 8];
#pragma unroll
    for (int n = 0; n < 4; ++n)
      bfv[n] = *(const bf16x8*)&Bs[(wc + n * 16 + cl) * 32 + g * 8];
#pragma unroll
    for (int m = 0; m < 4; ++m)
#pragma unroll
      for (int n = 0; n < 4; ++n)
        acc[m][n] = __builtin_amdgcn_mfma_f32_16x16x32_bf16(af[m], bfv[n], acc[m][n], 0, 0, 0);
    __syncthreads();            // all reads done before next stage
  }

  if (n0 < QDIM) {
    // ---- q: RoPE in-register; wave covers exactly one head (64 cols) ----
    const int colbase = n0 + wc;    // head*64
#pragma unroll
    for (int m = 0; m < 4; ++m)
#pragma unroll
      for (int n = 0; n < 2; ++n) {
        const int d = n * 16 + cl;
#pragma unroll
        for (int p = 0; p < 4; ++p) {
          int row = m0 + wr + m * 16 + g * 4 + p;
          int s = row & (SLEN - 1);
          float2 csn = tab[s * 32 + d];
          float a = acc[m][n][p], b = acc[m][n + 2][p];
          qb[(size_t)row * QDIM + colbase + d]      = f2bf(a * csn.x - b * csn.y);
          qb[(size_t)row * QDIM + colbase + d + 32] = f2bf(b * csn.x + a * csn.y);
        }
      }
  } else if (n0 < QDIM + KVDIM) {
    // ---- k: RoPE, stride 512 ----
    const int colbase = n0 - QDIM + wc;
#pragma unroll
    for (int m = 0; m < 4; ++m)
#pragma unroll
      for (int n = 0; n < 2; ++n) {
        const int d = n * 16 + cl;
#pragma unroll
        for (int p = 0; p < 4; ++p) {
          int row = m0 + wr + m * 16 + g * 4 + p;
          int s = row & (SLEN - 1);
          float2 csn = tab[s * 32 + d];
          float a = acc[m][n][p], b = acc[m][n + 2][p];
          kb[(size_t)row * KVDIM + colbase + d]      = f2bf(a * csn.x - b * csn.y);
          kb[(size_t)row * KVDIM + colbase + d + 32] = f2bf(b * csn.x + a * csn.y);
        }
      }
  } else {
    // ---- v: transposed write vt[b][kvh][d][s] ----
    const int colbase = n0 - QDIM - KVDIM + wc;
#pragma unroll
    for (int m = 0; m < 4; ++m)
#pragma unroll
      for (int n = 0; n < 4; ++n) {
        int col = colbase + n * 16 + cl;            // kvh*64 + d
        int kvh = col >> 6, d = col & 63;
        int row0 = m0 + wr + m * 16 + g * 4;        // 4 consecutive rows
        int bb = row0 >> 11, s = row0 & (SLEN - 1);
        unsigned short* dst = vt + (((size_t)(bb * NKV + kvh) * HD + d) << 11) + s;
        uint2 u;
        u.x = pk2(acc[m][n][0], acc[m][n][1]);
        u.y = pk2(acc[m][n][2], acc[m][n][3]);
        *(uint2*)dst = u;
      }
  }
}

// ---------------- Flash attention, sliding window --------------------------
__global__ __launch_bounds__(256) void attn(
    const unsigned short* __restrict__ qb, const unsigned short* __restrict__ kb,
    const unsigned short* __restrict__ vt, unsigned short* __restrict__ ao)
{
  __shared__ __align__(16) unsigned short Plds[4][16][40];
  const int lane = threadIdx.x & 63, wid = threadIdx.x >> 6;
  const int g = lane >> 4, cl = lane & 15;
  const int qt = blockIdx.x * 4 + wid;         // 0..8191
  const int bh = qt >> 7, tl = qt & 127;
  const int i0 = tl * 16;
  const int b = bh >> 5, h = bh & 31, kvh = (bh & 31) >> 2;
  const int qi = i0 + cl;

  const unsigned short* qp = qb + ((size_t)(b * SLEN + i0 + cl) * NH + h) * HD + g * 8;
  bf16x8 qf0 = *(const bf16x8*)qp;
  bf16x8 qf1 = *(const bf16x8*)(qp + 32);

  f32x4 acc_o[4] = {};
  float m_run = -1e30f, l_run = 0.f;
  int jb = i0 - WINH; if (jb < 0) jb = 0;

  for (int j0 = jb; j0 <= i0; j0 += 32) {
    f32x4 sacc[2];
#pragma unroll
    for (int t = 0; t < 2; ++t) {
      int krow = j0 + 16 * t + cl;
      if (krow > SLEN - 1) krow = SLEN - 1;
      const unsigned short* kp = kb + ((size_t)(b * SLEN + krow) * NKV + kvh) * HD + g * 8;
      bf16x8 kf0 = *(const bf16x8*)kp;
      bf16x8 kf1 = *(const bf16x8*)(kp + 32);
      f32x4 z = {};
      z = __builtin_amdgcn_mfma_f32_16x16x32_bf16(kf0, qf0, z, 0, 0, 0);
      z = __builtin_amdgcn_mfma_f32_16x16x32_bf16(kf1, qf1, z, 0, 0, 0);
      sacc[t] = z;
    }
    float s[2][4];
    float mx = -1e30f;
#pragma unroll
    for (int t = 0; t < 2; ++t)
#pragma unroll
      for (int p = 0; p < 4; ++p) {
        int kj = j0 + 16 * t + g * 4 + p;
        bool ok = (kj <= qi) && (qi - kj <= WINH);
        float v = ok ? sacc[t][p] * 0.125f : -1e30f;
        s[t][p] = v;
        mx = fmaxf(mx, v);
      }
    mx = fmaxf(mx, __shfl_xor(mx, 16));
    mx = fmaxf(mx, __shfl_xor(mx, 32));
    float mnew = fmaxf(m_run, mx);
    float corr = __expf(m_run - mnew);
    float ps = 0.f;
    unsigned pw[2][2];
#pragma unroll
    for (int t = 0; t < 2; ++t) {
      float p0 = __expf(s[t][0] - mnew);
      float p1 = __expf(s[t][1] - mnew);
      float p2 = __expf(s[t][2] - mnew);
      float p3 = __expf(s[t][3] - mnew);
      ps += p0 + p1 + p2 + p3;
      pw[t][0] = pk2(p0, p1);
      pw[t][1] = pk2(p2, p3);
    }
    ps += __shfl_xor(ps, 16);
    ps += __shfl_xor(ps, 32);
    l_run = l_run * corr + ps;
    m_run = mnew;
#pragma unroll
    for (int vbk = 0; vbk < 4; ++vbk)
#pragma unroll
      for (int p = 0; p < 4; ++p) acc_o[vbk][p] *= corr;
#pragma unroll
    for (int t = 0; t < 2; ++t) {
      *(unsigned*)&Plds[wid][cl][16 * t + 4 * g]     = pw[t][0];
      *(unsigned*)&Plds[wid][cl][16 * t + 4 * g + 2] = pw[t][1];
    }
    bf16x8 pf = *(const bf16x8*)&Plds[wid][cl][g * 8];
    int jv = j0 + g * 8;
    if (jv > SLEN - 8) jv = SLEN - 8;
    const unsigned short* vbase = vt + ((size_t)(b * NKV + kvh) * HD) * SLEN + jv;
#pragma unroll
    for (int vbk = 0; vbk < 4; ++vbk) {
      bf16x8 vf = *(const bf16x8*)(vbase + (size_t)(vbk * 16 + cl) * SLEN);
      acc_o[vbk] = __builtin_amdgcn_mfma_f32_16x16x32_bf16(vf, pf, acc_o[vbk], 0, 0, 0);
    }
  }
  float inv = 1.0f / l_run;
  unsigned short* op = ao + ((size_t)(b * SLEN + i0 + cl) * NH + h) * HD;
#pragma unroll
  for (int vbk = 0; vbk < 4; ++vbk) {
    unsigned u0 = pk2(acc_o[vbk][0] * inv, acc_o[vbk][1] * inv);
    unsigned u1 = pk2(acc_o[vbk][2] * inv, acc_o[vbk][3] * inv);
    *(unsigned*)(op + vbk * 16 + g * 4)     = u0;
    *(unsigned*)(op + vbk * 16 + g * 4 + 2) = u1;
  }
}

// ---------------- Output GEMM (m97 structure): fp32 out --------------------
__global__ __launch_bounds__(256) void out_gemm(
    const unsigned short* __restrict__ ao, const unsigned short* __restrict__ wob,
    float* __restrict__ out)
{
  __shared__ __align__(16) unsigned short As[128 * 32];
  __shared__ __align__(16) unsigned short Bs[128 * 32];
  const int m0 = blockIdx.x * 128;
  const int n0 = blockIdx.y * 128;
  const int tid = threadIdx.x;
  const int lane = tid & 63, wid = tid >> 6;
  const int g = lane >> 4, cl = lane & 15;
  const int wr = (wid >> 1) * 64, wc = (wid & 1) * 64;

  const int srow = wid * 32 + (lane >> 2);
  const int scol = (lane & 3) * 8;
  const unsigned short* ga = ao + (size_t)(m0 + srow) * 2048 + scol;
  const unsigned short* gb = wob + (size_t)(n0 + srow) * 2048 + scol;
  unsigned short* lA = &As[wid * 1024];
  unsigned short* lB = &Bs[wid * 1024];

  f32x4 acc[4][4] = {};
  for (int k0 = 0; k0 < 2048; k0 += 32) {
    async16(ga + k0, lA);
    async16(ga + k0 + (size_t)16 * 2048, lA + 512);
    async16(gb + k0, lB);
    async16(gb + k0 + (size_t)16 * 2048, lB + 512);
    __syncthreads();
    bf16x8 af[4], bfv[4];
#pragma unroll
    for (int m = 0; m < 4; ++m)
      af[m] = *(const bf16x8*)&As[(wr + m * 16 + cl) * 32 + g * 8];
#pragma unroll
    for (int n = 0; n < 4; ++n)
      bfv[n] = *(const bf16x8*)&Bs[(wc + n * 16 + cl) * 32 + g * 8];
#pragma unroll
    for (int m = 0; m < 4; ++m)
#pragma unroll
      for (int n = 0; n < 4; ++n)
        acc[m][n] = __builtin_amdgcn_mfma_f32_16x16x32_bf16(af[m], bfv[n], acc[m][n], 0, 0, 0);
    __syncthreads();
  }
#pragma unroll
  for (int m = 0; m < 4; ++m)
#pragma unroll
    for (int n = 0; n < 4; ++n)
#pragma unroll
      for (int p = 0; p < 4; ++p) {
        int row = m0 + wr + m * 16 + g * 4 + p;
        int col = n0 + wc + n * 16 + cl;
        out[(size_t)row * 2048 + col] = acc[m][n][p];
      }
}

// ---------------- launch ---------------------------------------------------
extern "C" void kernel_launch(void* const* d_in, const int* in_sizes, int n_in,
                              void* d_out, int out_size, void* d_ws, size_t ws_size,
                              hipStream_t stream) {
  const float* x  = (const float*)d_in[0];
  const float* wq = (const float*)d_in[1];
  const float* wk = (const float*)d_in[2];
  const float* wv = (const float*)d_in[3];
  const float* wo = (const float*)d_in[4];
  float* out = (float*)d_out;

  char* w = (char*)d_ws;
  unsigned short* wqkvb = (unsigned short*)w; w += (size_t)3072 * 2048 * 2;   // 12 MB
  unsigned short* xb    = (unsigned short*)w; w += (size_t)MROWS * QDIM * 2;  // 16 MB
  unsigned short* qb    = (unsigned short*)w; w += (size_t)MROWS * QDIM * 2;  // 16 MB
  unsigned short* kb    = (unsigned short*)w; w += (size_t)MROWS * KVDIM * 2; // 4 MB
  unsigned short* vt    = (unsigned short*)w; w += (size_t)MROWS * KVDIM * 2; // 4 MB
  float* tab            = (float*)w;          w += (size_t)SLEN * 32 * 8;     // 0.5 MB
  // aliases (lifetimes disjoint in stream order):
  unsigned short* wob = wqkvb;   // wo bf16 (8 MB) — written after qkv_gemm reads wqkvb
  unsigned short* ao  = xb;      // attn output — written after qkv_gemm reads xb

  rope_table<<<SLEN * 32 / 256, 256, 0, stream>>>((float2*)tab);
  conv_bf16<<<(MROWS * 2048) / (8 * 256), 256, 0, stream>>>(x, xb);
  conv_wqkv<<<(3072 * 2048) / (8 * 256), 256, 0, stream>>>(wq, wk, wv, wqkvb);
  qkv_gemm<<<dim3(MROWS / 128, 3072 / 128), 256, 0, stream>>>(
      xb, wqkvb, tab, qb, kb, vt);
  conv_bf16<<<(2048 * 2048) / (8 * 256), 256, 0, stream>>>(wo, wob);
  attn<<<(NB * NH * (SLEN / 16)) / 4, 256, 0, stream>>>(qb, kb, vt, ao);
  out_gemm<<<dim3(MROWS / 128, QDIM / 128), 256, 0, stream>>>(ao, wob, out);
}

// Round 3
// 219.410 us; speedup vs baseline: 1.2635x; 1.0418x over previous
//
#include <hip/hip_runtime.h>
#include <cstdint>
#include <cstddef>

#define SLEN 2048
#define NB 2
#define NH 32
#define NKV 8
#define HD 64
#define MROWS 4096   // NB*SLEN
#define QDIM 2048    // NH*HD
#define KVDIM 512    // NKV*HD
#define WINH 256     // WIN/2

typedef float f32x4 __attribute__((ext_vector_type(4)));
typedef __bf16 bf16x8 __attribute__((ext_vector_type(8)));

__device__ __forceinline__ unsigned short f2bf(float f) {
  union { float f; unsigned u; } v; v.f = f;
  unsigned r = v.u + 0x7fffu + ((v.u >> 16) & 1u);
  return (unsigned short)(r >> 16);
}
__device__ __forceinline__ float bf2f(unsigned short h) {
  union { unsigned u; float f; } v; v.u = ((unsigned)h) << 16;
  return v.f;
}
__device__ __forceinline__ unsigned pk2(float a, float b) {
  return (unsigned)f2bf(a) | ((unsigned)f2bf(b) << 16);
}
__device__ __forceinline__ uint4 cvt16(float4 a, float4 b) {
  uint4 u;
  u.x = pk2(a.x, a.y); u.y = pk2(a.z, a.w);
  u.z = pk2(b.x, b.y); u.w = pk2(b.z, b.w);
  return u;
}
// async global->LDS, 16B per lane; LDS dest is wave-uniform base + lane*16
__device__ __forceinline__ void async16(const unsigned short* g, unsigned short* l) {
  __builtin_amdgcn_global_load_lds(
      (const __attribute__((address_space(1))) unsigned int*)g,
      (__attribute__((address_space(3))) unsigned int*)l, 16, 0, 0);
}

// ---------------- RoPE table: tab[s*32+d] = {cos, sin} ---------------------
__global__ void rope_table(float2* __restrict__ tab) {
  int tid = blockIdx.x * 256 + threadIdx.x;      // 2048*32 = 65536
  int d = tid & 31;
  int s = tid >> 5;
  float inv = expf((float)d * (-2.0f / 64.0f) * 9.210340371976184f);
  float ang = (float)s * inv;
  float sn, cs;
  sincosf(ang, &sn, &cs);
  tab[tid] = make_float2(cs, sn);
}

// ---------------- fp32 -> bf16 converters ----------------------------------
__global__ void conv_bf16(const float* __restrict__ src, unsigned short* __restrict__ dst) {
  size_t t = (size_t)blockIdx.x * 256 + threadIdx.x;
  float4 a = *(const float4*)(src + t * 8);
  float4 b = *(const float4*)(src + t * 8 + 4);
  *(uint4*)(dst + t * 8) = cvt16(a, b);
}

__global__ void conv_wqkv(const float* __restrict__ wq, const float* __restrict__ wk,
                          const float* __restrict__ wv, unsigned short* __restrict__ dst) {
  size_t t = (size_t)blockIdx.x * 256 + threadIdx.x;   // 786432 threads
  size_t e = t * 8;
  int row = (int)(e >> 11);
  const float* src; size_t off;
  if (row < 2048)       { src = wq; off = e; }
  else if (row < 2560)  { src = wk; off = e - (size_t)2048 * 2048; }
  else                  { src = wv; off = e - (size_t)2560 * 2048; }
  float4 a = *(const float4*)(src + off);
  float4 b = *(const float4*)(src + off + 4);
  *(uint4*)(dst + e) = cvt16(a, b);
}

// ======================= 256x256 8-phase GEMM (T2+T3+T4+T5) ================
// BM=BN=256, BK=64, 8 waves (2M x 4N), per-wave 128x64 output, 128 KiB LDS.
// LDS regions: [dbuf][op A=0/B=1][khalf] of 8192 ushort (256 rows x 32 k).
// Swizzle: 16B k-slot XOR'd with (row>>1)&3 -> conflict-free quarter-wave
// ds_read_b128. Staging keeps LDS linear and pre-swizzles the GLOBAL source.
// Schedule (per K-tile t, verified R/W-hazard-free):
//   p1 (mh0,k0): stage A-k1(t+1)   p2 (mh1,k0): stage B-k1(t+1)
//   p3 (mh0,k1): stage A-k0(t+2)   p4 (mh1,k1): stage B-k0(t+2) + vmcnt(4)
// KIND 0: qkv (+fused RoPE on q/k, transposed V write). KIND 1: fp32 out-proj.
template <int KIND>
__global__ __launch_bounds__(512, 2) void gemm256(
    const unsigned short* __restrict__ Ap, const unsigned short* __restrict__ Bp,
    const float* __restrict__ tabf,
    unsigned short* __restrict__ o_q, unsigned short* __restrict__ o_k,
    unsigned short* __restrict__ o_v, float* __restrict__ o_f)
{
  extern __shared__ unsigned short L[];
  constexpr int NBM = 16;
  constexpr int NBN = (KIND == 0) ? 12 : 8;
  constexpr int NWG = NBM * NBN;     // 192 / 128, both % 8 == 0
  constexpr int NT = 32;             // K = 2048 / 64

  const int bid = blockIdx.x;
  const int swz = (bid & 7) * (NWG >> 3) + (bid >> 3);   // XCD-aware, bijective
  const int bm0 = (swz & 15) * 256;
  const int bn0 = (swz >> 4) * 256;

  const int tid = threadIdx.x;
  const int lane = tid & 63, wid = tid >> 6;
  const int g = lane >> 4, cl = lane & 15;
  const int wm = wid >> 2, wn = wid & 3;

  // staging lane geometry: LDS lands linearly; global source pre-swizzled
  const int r0 = wid * 32 + (lane >> 2);
  const int s0 = (((lane & 3) ^ ((lane >> 3) & 3)) << 3);
  const unsigned short* gA = Ap + (size_t)(bm0 + r0) * 2048 + s0;
  const unsigned short* gB = Bp + (size_t)(bn0 + r0) * 2048 + s0;

  // read lane geometry (ushort idx); k-slot swizzled by (row>>1)&3 = (cl>>1)&3
  const int slotus = ((g ^ ((cl >> 1) & 3)) << 3);
  const int aread = (wm * 128 + cl) * 32 + slotus;
  const int bread = (wn * 64 + cl) * 32 + slotus;

#define REG_(b, op, kh) ((((b) * 2 + (op)) * 2 + (kh)) * 8192)
#define STG(op, kh, tt, db) do { \
    const unsigned short* s_ = ((op) ? gB : gA) + (tt) * 64 + (kh) * 32; \
    unsigned short* d_ = L + REG_(db, op, kh) + wid * 1024; \
    async16(s_, d_); \
    async16(s_ + 16 * 2048, d_ + 512); \
  } while (0)

  f32x4 acc[8][4] = {};

  // prologue: tile0 fully + tile1 k0 halves; vmcnt(4) leaves tile1-k0 in flight
  STG(0, 0, 0, 0); STG(1, 0, 0, 0); STG(0, 1, 0, 0); STG(1, 1, 0, 0);
  STG(0, 0, 1, 1); STG(1, 0, 1, 1);
  asm volatile("s_waitcnt vmcnt(4)" ::: "memory");
  __builtin_amdgcn_s_barrier();

#define PHASE(mh, kh, STAGE_STMT, VMW) do { \
    bf16x8 af[4], bv[4]; \
    const int ab_ = REG_(cb, 0, kh) + aread + (mh) * 2048; \
    const int bb_ = REG_(cb, 1, kh) + bread; \
    _Pragma("unroll") for (int mf = 0; mf < 4; ++mf) \
      af[mf] = *(const bf16x8*)&L[ab_ + mf * 512]; \
    _Pragma("unroll") for (int nf = 0; nf < 4; ++nf) \
      bv[nf] = *(const bf16x8*)&L[bb_ + nf * 512]; \
    STAGE_STMT; \
    VMW; \
    __builtin_amdgcn_s_barrier(); \
    asm volatile("s_waitcnt lgkmcnt(0)" ::: "memory"); \
    __builtin_amdgcn_sched_barrier(0); \
    __builtin_amdgcn_s_setprio(1); \
    _Pragma("unroll") for (int mf = 0; mf < 4; ++mf) \
      _Pragma("unroll") for (int nf = 0; nf < 4; ++nf) \
        acc[(mh) * 4 + mf][nf] = __builtin_amdgcn_mfma_f32_16x16x32_bf16( \
            af[mf], bv[nf], acc[(mh) * 4 + mf][nf], 0, 0, 0); \
    __builtin_amdgcn_s_setprio(0); \
    __builtin_amdgcn_sched_barrier(0); \
    __builtin_amdgcn_s_barrier(); \
  } while (0)

#pragma unroll 1
  for (int t = 0; t < NT; ++t) {
    const int cb = t & 1, nb = cb ^ 1;
    PHASE(0, 0, if (t + 1 < NT) STG(0, 1, t + 1, nb), );
    PHASE(1, 0, if (t + 1 < NT) STG(1, 1, t + 1, nb), );
    PHASE(0, 1, if (t + 2 < NT) STG(0, 0, t + 2, cb), );
    PHASE(1, 1, if (t + 2 < NT) STG(1, 0, t + 2, cb),
          if (t + 2 < NT) { asm volatile("s_waitcnt vmcnt(4)" ::: "memory"); }
          else            { asm volatile("s_waitcnt vmcnt(0)" ::: "memory"); });
  }
#undef PHASE
#undef STG
#undef REG_

  // ---------------- epilogue ----------------
  const int rb = bm0 + wm * 128;
  if (KIND == 0) {
    const float2* tab = (const float2*)tabf;
    if (bn0 < QDIM) {
      const int colb = bn0 + wn * 64;       // head*64
#pragma unroll
      for (int m = 0; m < 8; ++m)
#pragma unroll
        for (int nf = 0; nf < 2; ++nf) {
          const int d = nf * 16 + cl;
#pragma unroll
          for (int p = 0; p < 4; ++p) {
            int row = rb + m * 16 + g * 4 + p;
            int s = row & (SLEN - 1);
            float2 cs = tab[s * 32 + d];
            float a = acc[m][nf][p], b2 = acc[m][nf + 2][p];
            o_q[(size_t)row * QDIM + colb + d]      = f2bf(a * cs.x - b2 * cs.y);
            o_q[(size_t)row * QDIM + colb + d + 32] = f2bf(b2 * cs.x + a * cs.y);
          }
        }
    } else if (bn0 < QDIM + KVDIM) {
      const int colb = bn0 - QDIM + wn * 64;
#pragma unroll
      for (int m = 0; m < 8; ++m)
#pragma unroll
        for (int nf = 0; nf < 2; ++nf) {
          const int d = nf * 16 + cl;
#pragma unroll
          for (int p = 0; p < 4; ++p) {
            int row = rb + m * 16 + g * 4 + p;
            int s = row & (SLEN - 1);
            float2 cs = tab[s * 32 + d];
            float a = acc[m][nf][p], b2 = acc[m][nf + 2][p];
            o_k[(size_t)row * KVDIM + colb + d]      = f2bf(a * cs.x - b2 * cs.y);
            o_k[(size_t)row * KVDIM + colb + d + 32] = f2bf(b2 * cs.x + a * cs.y);
          }
        }
    } else {
      const int colb = bn0 - QDIM - KVDIM + wn * 64;
#pragma unroll
      for (int m = 0; m < 8; ++m)
#pragma unroll
        for (int nf = 0; nf < 4; ++nf) {
          int col = colb + nf * 16 + cl;          // kvh*64 + d
          int kvh = col >> 6, d = col & 63;
          int row0 = rb + m * 16 + g * 4;
          int bb = row0 >> 11, s = row0 & (SLEN - 1);
          unsigned short* dst = o_v + (((size_t)(bb * NKV + kvh) * HD + d) << 11) + s;
          uint2 u;
          u.x = pk2(acc[m][nf][0], acc[m][nf][1]);
          u.y = pk2(acc[m][nf][2], acc[m][nf][3]);
          *(uint2*)dst = u;
        }
    }
  } else {
    const int colb = bn0 + wn * 64;
#pragma unroll
    for (int m = 0; m < 8; ++m)
#pragma unroll
      for (int nf = 0; nf < 4; ++nf)
#pragma unroll
        for (int p = 0; p < 4; ++p) {
          int row = rb + m * 16 + g * 4 + p;
          o_f[(size_t)row * 2048 + colb + nf * 16 + cl] = acc[m][nf][p];
        }
  }
}

// ---------------- Flash attention, sliding window --------------------------
__global__ __launch_bounds__(256) void attn(
    const unsigned short* __restrict__ qb, const unsigned short* __restrict__ kb,
    const unsigned short* __restrict__ vt, unsigned short* __restrict__ ao)
{
  __shared__ __align__(16) unsigned short Plds[4][16][40];
  const int lane = threadIdx.x & 63, wid = threadIdx.x >> 6;
  const int g = lane >> 4, cl = lane & 15;
  const int qt = blockIdx.x * 4 + wid;         // 0..8191
  const int bh = qt >> 7, tl = qt & 127;
  const int i0 = tl * 16;
  const int b = bh >> 5, h = bh & 31, kvh = (bh & 31) >> 2;
  const int qi = i0 + cl;

  const unsigned short* qp = qb + ((size_t)(b * SLEN + i0 + cl) * NH + h) * HD + g * 8;
  bf16x8 qf0 = *(const bf16x8*)qp;
  bf16x8 qf1 = *(const bf16x8*)(qp + 32);

  f32x4 acc_o[4] = {};
  float m_run = -1e30f, l_run = 0.f;
  int jb = i0 - WINH; if (jb < 0) jb = 0;

  for (int j0 = jb; j0 <= i0; j0 += 32) {
    f32x4 sacc[2];
#pragma unroll
    for (int t = 0; t < 2; ++t) {
      int krow = j0 + 16 * t + cl;
      if (krow > SLEN - 1) krow = SLEN - 1;
      const unsigned short* kp = kb + ((size_t)(b * SLEN + krow) * NKV + kvh) * HD + g * 8;
      bf16x8 kf0 = *(const bf16x8*)kp;
      bf16x8 kf1 = *(const bf16x8*)(kp + 32);
      f32x4 z = {};
      z = __builtin_amdgcn_mfma_f32_16x16x32_bf16(kf0, qf0, z, 0, 0, 0);
      z = __builtin_amdgcn_mfma_f32_16x16x32_bf16(kf1, qf1, z, 0, 0, 0);
      sacc[t] = z;
    }
    float s[2][4];
    float mx = -1e30f;
#pragma unroll
    for (int t = 0; t < 2; ++t)
#pragma unroll
      for (int p = 0; p < 4; ++p) {
        int kj = j0 + 16 * t + g * 4 + p;
        bool ok = (kj <= qi) && (qi - kj <= WINH);
        float v = ok ? sacc[t][p] * 0.125f : -1e30f;
        s[t][p] = v;
        mx = fmaxf(mx, v);
      }
    mx = fmaxf(mx, __shfl_xor(mx, 16));
    mx = fmaxf(mx, __shfl_xor(mx, 32));
    float mnew = fmaxf(m_run, mx);
    float corr = __expf(m_run - mnew);
    float ps = 0.f;
    unsigned pw[2][2];
#pragma unroll
    for (int t = 0; t < 2; ++t) {
      float p0 = __expf(s[t][0] - mnew);
      float p1 = __expf(s[t][1] - mnew);
      float p2 = __expf(s[t][2] - mnew);
      float p3 = __expf(s[t][3] - mnew);
      ps += p0 + p1 + p2 + p3;
      pw[t][0] = pk2(p0, p1);
      pw[t][1] = pk2(p2, p3);
    }
    ps += __shfl_xor(ps, 16);
    ps += __shfl_xor(ps, 32);
    l_run = l_run * corr + ps;
    m_run = mnew;
#pragma unroll
    for (int vbk = 0; vbk < 4; ++vbk)
#pragma unroll
      for (int p = 0; p < 4; ++p) acc_o[vbk][p] *= corr;
#pragma unroll
    for (int t = 0; t < 2; ++t) {
      *(unsigned*)&Plds[wid][cl][16 * t + 4 * g]     = pw[t][0];
      *(unsigned*)&Plds[wid][cl][16 * t + 4 * g + 2] = pw[t][1];
    }
    bf16x8 pf = *(const bf16x8*)&Plds[wid][cl][g * 8];
    int jv = j0 + g * 8;
    if (jv > SLEN - 8) jv = SLEN - 8;
    const unsigned short* vbase = vt + ((size_t)(b * NKV + kvh) * HD) * SLEN + jv;
#pragma unroll
    for (int vbk = 0; vbk < 4; ++vbk) {
      bf16x8 vf = *(const bf16x8*)(vbase + (size_t)(vbk * 16 + cl) * SLEN);
      acc_o[vbk] = __builtin_amdgcn_mfma_f32_16x16x32_bf16(vf, pf, acc_o[vbk], 0, 0, 0);
    }
  }
  float inv = 1.0f / l_run;
  unsigned short* op = ao + ((size_t)(b * SLEN + i0 + cl) * NH + h) * HD;
#pragma unroll
  for (int vbk = 0; vbk < 4; ++vbk) {
    unsigned u0 = pk2(acc_o[vbk][0] * inv, acc_o[vbk][1] * inv);
    unsigned u1 = pk2(acc_o[vbk][2] * inv, acc_o[vbk][3] * inv);
    *(unsigned*)(op + vbk * 16 + g * 4)     = u0;
    *(unsigned*)(op + vbk * 16 + g * 4 + 2) = u1;
  }
}

// ---------------- launch ---------------------------------------------------
extern "C" void kernel_launch(void* const* d_in, const int* in_sizes, int n_in,
                              void* d_out, int out_size, void* d_ws, size_t ws_size,
                              hipStream_t stream) {
  const float* x  = (const float*)d_in[0];
  const float* wq = (const float*)d_in[1];
  const float* wk = (const float*)d_in[2];
  const float* wv = (const float*)d_in[3];
  const float* wo = (const float*)d_in[4];
  float* out = (float*)d_out;

  char* w = (char*)d_ws;
  unsigned short* wqkvb = (unsigned short*)w; w += (size_t)3072 * 2048 * 2;   // 12 MB
  unsigned short* xb    = (unsigned short*)w; w += (size_t)MROWS * QDIM * 2;  // 16 MB
  unsigned short* qb    = (unsigned short*)w; w += (size_t)MROWS * QDIM * 2;  // 16 MB
  unsigned short* kb    = (unsigned short*)w; w += (size_t)MROWS * KVDIM * 2; // 4 MB
  unsigned short* vt    = (unsigned short*)w; w += (size_t)MROWS * KVDIM * 2; // 4 MB
  float* tab            = (float*)w;          w += (size_t)SLEN * 32 * 8;     // 0.5 MB
  // aliases (lifetimes disjoint in stream order):
  unsigned short* wob = wqkvb;   // wo bf16 — written after qkv_gemm reads wqkvb
  unsigned short* ao  = xb;      // attn output — written after qkv_gemm reads xb

  hipFuncSetAttribute((const void*)gemm256<0>,
                      hipFuncAttributeMaxDynamicSharedMemorySize, 131072);
  hipFuncSetAttribute((const void*)gemm256<1>,
                      hipFuncAttributeMaxDynamicSharedMemorySize, 131072);

  rope_table<<<SLEN * 32 / 256, 256, 0, stream>>>((float2*)tab);
  conv_bf16<<<(MROWS * 2048) / (8 * 256), 256, 0, stream>>>(x, xb);
  conv_wqkv<<<(3072 * 2048) / (8 * 256), 256, 0, stream>>>(wq, wk, wv, wqkvb);
  gemm256<0><<<192, 512, 131072, stream>>>(xb, wqkvb, tab, qb, kb, vt, nullptr);
  conv_bf16<<<(2048 * 2048) / (8 * 256), 256, 0, stream>>>(wo, wob);
  attn<<<(NB * NH * (SLEN / 16)) / 4, 256, 0, stream>>>(qb, kb, vt, ao);
  gemm256<1><<<128, 512, 131072, stream>>>(ao, wob, nullptr, nullptr, nullptr, nullptr, out);
}

// Round 4
// 202.658 us; speedup vs baseline: 1.3679x; 1.0827x over previous
//
#include <hip/hip_runtime.h>
#include <cstdint>
#include <cstddef>

#define SLEN 2048
#define NB 2
#define NH 32
#define NKV 8
#define HD 64
#define MROWS 4096   // NB*SLEN
#define QDIM 2048    // NH*HD
#define KVDIM 512    // NKV*HD
#define WINH 256     // WIN/2

typedef float f32x4 __attribute__((ext_vector_type(4)));
typedef __bf16 bf16x8 __attribute__((ext_vector_type(8)));

__device__ __forceinline__ unsigned short f2bf(float f) {
  union { float f; unsigned u; } v; v.f = f;
  unsigned r = v.u + 0x7fffu + ((v.u >> 16) & 1u);
  return (unsigned short)(r >> 16);
}
__device__ __forceinline__ float bf2f(unsigned short h) {
  union { unsigned u; float f; } v; v.u = ((unsigned)h) << 16;
  return v.f;
}
__device__ __forceinline__ unsigned pk2(float a, float b) {
  return (unsigned)f2bf(a) | ((unsigned)f2bf(b) << 16);
}
__device__ __forceinline__ uint4 cvt16(float4 a, float4 b) {
  uint4 u;
  u.x = pk2(a.x, a.y); u.y = pk2(a.z, a.w);
  u.z = pk2(b.x, b.y); u.w = pk2(b.z, b.w);
  return u;
}
// async global->LDS, 16B per lane; LDS dest is wave-uniform base + lane*16
__device__ __forceinline__ void async16(const unsigned short* g, unsigned short* l) {
  __builtin_amdgcn_global_load_lds(
      (const __attribute__((address_space(1))) unsigned int*)g,
      (__attribute__((address_space(3))) unsigned int*)l, 16, 0, 0);
}

// ---------------- RoPE table: tab[s*32+d] = {cos, sin} ---------------------
__global__ void rope_table(float2* __restrict__ tab) {
  int tid = blockIdx.x * 256 + threadIdx.x;      // 2048*32 = 65536
  int d = tid & 31;
  int s = tid >> 5;
  float inv = expf((float)d * (-2.0f / 64.0f) * 9.210340371976184f);
  float ang = (float)s * inv;
  float sn, cs;
  sincosf(ang, &sn, &cs);
  tab[tid] = make_float2(cs, sn);
}

// ---------------- fp32 -> bf16 converters ----------------------------------
__global__ void conv_bf16(const float* __restrict__ src, unsigned short* __restrict__ dst) {
  size_t t = (size_t)blockIdx.x * 256 + threadIdx.x;
  float4 a = *(const float4*)(src + t * 8);
  float4 b = *(const float4*)(src + t * 8 + 4);
  *(uint4*)(dst + t * 8) = cvt16(a, b);
}

__global__ void conv_wqkv(const float* __restrict__ wq, const float* __restrict__ wk,
                          const float* __restrict__ wv, unsigned short* __restrict__ dst) {
  size_t t = (size_t)blockIdx.x * 256 + threadIdx.x;   // 786432 threads
  size_t e = t * 8;
  int row = (int)(e >> 11);
  const float* src; size_t off;
  if (row < 2048)       { src = wq; off = e; }
  else if (row < 2560)  { src = wk; off = e - (size_t)2048 * 2048; }
  else                  { src = wv; off = e - (size_t)2560 * 2048; }
  float4 a = *(const float4*)(src + off);
  float4 b = *(const float4*)(src + off + 4);
  *(uint4*)(dst + e) = cvt16(a, b);
}

// ======================= QKV GEMM: 256x256, 8-wave, 4-phase ================
// BM=BN=256, BK=64, per-wave 128x64 out, 128 KiB LDS, counted vmcnt.
// No explicit lgkmcnt / sched_barrier: C++ ds_reads let the compiler emit
// fine-grained lgkmcnt(N) interleaved with the MFMA cluster (m97 pattern).
__global__ __launch_bounds__(512, 2) void qkv_gemm(
    const unsigned short* __restrict__ Ap, const unsigned short* __restrict__ Bp,
    const float* __restrict__ tabf,
    unsigned short* __restrict__ o_q, unsigned short* __restrict__ o_k,
    unsigned short* __restrict__ o_v)
{
  extern __shared__ unsigned short L[];
  constexpr int NT = 32;             // K = 2048 / 64

  const int bid = blockIdx.x;        // 192 blocks (16 x 12), 192 % 8 == 0
  const int swz = (bid & 7) * 24 + (bid >> 3);
  const int bm0 = (swz & 15) * 256;
  const int bn0 = (swz >> 4) * 256;

  const int tid = threadIdx.x;
  const int lane = tid & 63, wid = tid >> 6;
  const int g = lane >> 4, cl = lane & 15;
  const int wm = wid >> 2, wn = wid & 3;

  // staging geometry: rows wid*32..+31, pre-swizzled global k-slot
  const int r0 = wid * 32 + (lane >> 2);
  const int s0 = (((lane & 3) ^ ((lane >> 3) & 3)) << 3);
  const unsigned short* gA = Ap + (size_t)(bm0 + r0) * 2048 + s0;
  const unsigned short* gB = Bp + (size_t)(bn0 + r0) * 2048 + s0;

  // read geometry; k-slot swizzled by (row>>1)&3 = (cl>>1)&3
  const int slotus = ((g ^ ((cl >> 1) & 3)) << 3);
  const int aread = (wm * 128 + cl) * 32 + slotus;
  const int bread = (wn * 64 + cl) * 32 + slotus;

#define REG_(b, op, kh) ((((b) * 2 + (op)) * 2 + (kh)) * 8192)
#define STG(op, kh, tt, db) do { \
    const unsigned short* s_ = ((op) ? gB : gA) + (tt) * 64 + (kh) * 32; \
    unsigned short* d_ = L + REG_(db, op, kh) + wid * 1024; \
    async16(s_, d_); \
    async16(s_ + 16 * 2048, d_ + 512); \
  } while (0)

  f32x4 acc[8][4] = {};

  // prologue: tile0 fully + tile1 k0; vmcnt(4) -> tile0 resident
  STG(0, 0, 0, 0); STG(1, 0, 0, 0); STG(0, 1, 0, 0); STG(1, 1, 0, 0);
  STG(0, 0, 1, 1); STG(1, 0, 1, 1);
  asm volatile("s_waitcnt vmcnt(4)" ::: "memory");
  __builtin_amdgcn_s_barrier();

#define PHASE(mh, kh, STAGE_STMT, VMW) do { \
    bf16x8 af[4], bv[4]; \
    const int ab_ = REG_(cb, 0, kh) + aread + (mh) * 2048; \
    const int bb_ = REG_(cb, 1, kh) + bread; \
    _Pragma("unroll") for (int mf = 0; mf < 4; ++mf) \
      af[mf] = *(const bf16x8*)&L[ab_ + mf * 512]; \
    _Pragma("unroll") for (int nf = 0; nf < 4; ++nf) \
      bv[nf] = *(const bf16x8*)&L[bb_ + nf * 512]; \
    STAGE_STMT; \
    VMW; \
    __builtin_amdgcn_s_barrier(); \
    __builtin_amdgcn_s_setprio(1); \
    _Pragma("unroll") for (int mf = 0; mf < 4; ++mf) \
      _Pragma("unroll") for (int nf = 0; nf < 4; ++nf) \
        acc[(mh) * 4 + mf][nf] = __builtin_amdgcn_mfma_f32_16x16x32_bf16( \
            af[mf], bv[nf], acc[(mh) * 4 + mf][nf], 0, 0, 0); \
    __builtin_amdgcn_s_setprio(0); \
    __builtin_amdgcn_s_barrier(); \
  } while (0)

#pragma unroll 1
  for (int t = 0; t < NT; ++t) {
    const int cb = t & 1, nb = cb ^ 1;
    PHASE(0, 0, if (t + 1 < NT) STG(0, 1, t + 1, nb), );
    PHASE(1, 0, if (t + 1 < NT) STG(1, 1, t + 1, nb), );
    PHASE(0, 1, if (t + 2 < NT) STG(0, 0, t + 2, cb), );
    PHASE(1, 1, if (t + 2 < NT) STG(1, 0, t + 2, cb),
          if (t + 2 < NT) { asm volatile("s_waitcnt vmcnt(4)" ::: "memory"); }
          else            { asm volatile("s_waitcnt vmcnt(0)" ::: "memory"); });
  }
#undef PHASE
#undef STG
#undef REG_

  // ---------------- epilogue: fused RoPE (q,k) / transposed V write --------
  const int rb = bm0 + wm * 128;
  const float2* tab = (const float2*)tabf;
  if (bn0 < QDIM) {
    const int colb = bn0 + wn * 64;       // head*64
#pragma unroll
    for (int m = 0; m < 8; ++m)
#pragma unroll
      for (int nf = 0; nf < 2; ++nf) {
        const int d = nf * 16 + cl;
#pragma unroll
        for (int p = 0; p < 4; ++p) {
          int row = rb + m * 16 + g * 4 + p;
          int s = row & (SLEN - 1);
          float2 cs = tab[s * 32 + d];
          float a = acc[m][nf][p], b2 = acc[m][nf + 2][p];
          o_q[(size_t)row * QDIM + colb + d]      = f2bf(a * cs.x - b2 * cs.y);
          o_q[(size_t)row * QDIM + colb + d + 32] = f2bf(b2 * cs.x + a * cs.y);
        }
      }
  } else if (bn0 < QDIM + KVDIM) {
    const int colb = bn0 - QDIM + wn * 64;
#pragma unroll
    for (int m = 0; m < 8; ++m)
#pragma unroll
      for (int nf = 0; nf < 2; ++nf) {
        const int d = nf * 16 + cl;
#pragma unroll
        for (int p = 0; p < 4; ++p) {
          int row = rb + m * 16 + g * 4 + p;
          int s = row & (SLEN - 1);
          float2 cs = tab[s * 32 + d];
          float a = acc[m][nf][p], b2 = acc[m][nf + 2][p];
          o_k[(size_t)row * KVDIM + colb + d]      = f2bf(a * cs.x - b2 * cs.y);
          o_k[(size_t)row * KVDIM + colb + d + 32] = f2bf(b2 * cs.x + a * cs.y);
        }
      }
  } else {
    const int colb = bn0 - QDIM - KVDIM + wn * 64;
#pragma unroll
    for (int m = 0; m < 8; ++m)
#pragma unroll
      for (int nf = 0; nf < 4; ++nf) {
        int col = colb + nf * 16 + cl;          // kvh*64 + d
        int kvh = col >> 6, d = col & 63;
        int row0 = rb + m * 16 + g * 4;
        int bb = row0 >> 11, s = row0 & (SLEN - 1);
        unsigned short* dst = o_v + (((size_t)(bb * NKV + kvh) * HD + d) << 11) + s;
        uint2 u;
        u.x = pk2(acc[m][nf][0], acc[m][nf][1]);
        u.y = pk2(acc[m][nf][2], acc[m][nf][3]);
        *(uint2*)dst = u;
      }
  }
}

// ======================= OUT GEMM: 128x256, 8-wave, 4-phase ================
// BM=128, BN=256 -> grid 32x8 = 256 blocks (all CUs). Per-wave 64x64,
// wave grid 2m x 4n. Phases = (m-pair, khalf): af[2]+bv[4], 8 MFMA.
// LDS 96 KiB: per buf {A:4096, B-k0:8192(off 8192), B-k1:8192} ushorts.
__global__ __launch_bounds__(512, 2) void out_gemm(
    const unsigned short* __restrict__ Ap, const unsigned short* __restrict__ Bp,
    float* __restrict__ o_f)
{
  extern __shared__ unsigned short L[];
  constexpr int NT = 32;

  const int bid = blockIdx.x;        // 256 blocks (32 x 8)
  const int swz = (bid & 7) * 32 + (bid >> 3);
  const int bm0 = (swz & 31) * 128;
  const int bn0 = (swz >> 5) * 256;

  const int tid = threadIdx.x;
  const int lane = tid & 63, wid = tid >> 6;
  const int g = lane >> 4, cl = lane & 15;
  const int wm = wid >> 2, wn = wid & 3;

  const int s0 = (((lane & 3) ^ ((lane >> 3) & 3)) << 3);
  const unsigned short* gA = Ap + (size_t)(bm0 + wid * 16 + (lane >> 2)) * 2048 + s0;
  const unsigned short* gB = Bp + (size_t)(bn0 + wid * 32 + (lane >> 2)) * 2048 + s0;

  const int slotus = ((g ^ ((cl >> 1) & 3)) << 3);
  const int aread = (wm * 64 + cl) * 32 + slotus;
  const int bread = (wn * 64 + cl) * 32 + slotus;

#define REGA_(b, kh) ((b) * 24576 + (kh) * 4096)
#define REGB_(b, kh) ((b) * 24576 + 8192 + (kh) * 8192)
#define STGA(kh, tt, db) \
    async16(gA + (tt) * 64 + (kh) * 32, L + REGA_(db, kh) + wid * 512)
#define STGB(kh, tt, db) do { \
    const unsigned short* s_ = gB + (tt) * 64 + (kh) * 32; \
    unsigned short* d_ = L + REGB_(db, kh) + wid * 1024; \
    async16(s_, d_); \
    async16(s_ + 16 * 2048, d_ + 512); \
  } while (0)

  f32x4 acc[4][4] = {};

  // prologue: tile0 (6 loads) + tile1-k0 (3 loads); vmcnt(3) -> tile0 resident
  STGA(0, 0, 0); STGB(0, 0, 0); STGA(1, 0, 0); STGB(1, 0, 0);
  STGA(0, 1, 1); STGB(0, 1, 1);
  asm volatile("s_waitcnt vmcnt(3)" ::: "memory");
  __builtin_amdgcn_s_barrier();

#define PHASE(mp, kh, STAGE_STMT, VMW) do { \
    bf16x8 af[2], bv[4]; \
    const int ab_ = REGA_(cb, kh) + aread + (mp) * 1024; \
    const int bb_ = REGB_(cb, kh) + bread; \
    _Pragma("unroll") for (int mf = 0; mf < 2; ++mf) \
      af[mf] = *(const bf16x8*)&L[ab_ + mf * 512]; \
    _Pragma("unroll") for (int nf = 0; nf < 4; ++nf) \
      bv[nf] = *(const bf16x8*)&L[bb_ + nf * 512]; \
    STAGE_STMT; \
    VMW; \
    __builtin_amdgcn_s_barrier(); \
    __builtin_amdgcn_s_setprio(1); \
    _Pragma("unroll") for (int mf = 0; mf < 2; ++mf) \
      _Pragma("unroll") for (int nf = 0; nf < 4; ++nf) \
        acc[(mp) * 2 + mf][nf] = __builtin_amdgcn_mfma_f32_16x16x32_bf16( \
            af[mf], bv[nf], acc[(mp) * 2 + mf][nf], 0, 0, 0); \
    __builtin_amdgcn_s_setprio(0); \
    __builtin_amdgcn_s_barrier(); \
  } while (0)

#pragma unroll 1
  for (int t = 0; t < NT; ++t) {
    const int cb = t & 1, nb = cb ^ 1;
    PHASE(0, 0, if (t + 1 < NT) STGA(1, t + 1, nb), );
    PHASE(1, 0, if (t + 1 < NT) STGB(1, t + 1, nb), );
    PHASE(0, 1, if (t + 2 < NT) STGA(0, t + 2, cb), );
    PHASE(1, 1, if (t + 2 < NT) STGB(0, t + 2, cb),
          if (t + 2 < NT) { asm volatile("s_waitcnt vmcnt(3)" ::: "memory"); }
          else            { asm volatile("s_waitcnt vmcnt(0)" ::: "memory"); });
  }
#undef PHASE
#undef STGA
#undef STGB
#undef REGA_
#undef REGB_

  const int rb = bm0 + wm * 64;
  const int colb = bn0 + wn * 64;
#pragma unroll
  for (int m = 0; m < 4; ++m)
#pragma unroll
    for (int nf = 0; nf < 4; ++nf)
#pragma unroll
      for (int p = 0; p < 4; ++p) {
        int row = rb + m * 16 + g * 4 + p;
        o_f[(size_t)row * 2048 + colb + nf * 16 + cl] = acc[m][nf][p];
      }
}

// ---------------- Flash attention, sliding window --------------------------
__global__ __launch_bounds__(256) void attn(
    const unsigned short* __restrict__ qb, const unsigned short* __restrict__ kb,
    const unsigned short* __restrict__ vt, unsigned short* __restrict__ ao)
{
  __shared__ __align__(16) unsigned short Plds[4][16][40];
  const int lane = threadIdx.x & 63, wid = threadIdx.x >> 6;
  const int g = lane >> 4, cl = lane & 15;
  const int qt = blockIdx.x * 4 + wid;         // 0..8191
  const int bh = qt >> 7, tl = qt & 127;
  const int i0 = tl * 16;
  const int b = bh >> 5, h = bh & 31, kvh = (bh & 31) >> 2;
  const int qi = i0 + cl;

  const unsigned short* qp = qb + ((size_t)(b * SLEN + i0 + cl) * NH + h) * HD + g * 8;
  bf16x8 qf0 = *(const bf16x8*)qp;
  bf16x8 qf1 = *(const bf16x8*)(qp + 32);

  f32x4 acc_o[4] = {};
  float m_run = -1e30f, l_run = 0.f;
  int jb = i0 - WINH; if (jb < 0) jb = 0;

  for (int j0 = jb; j0 <= i0; j0 += 32) {
    f32x4 sacc[2];
#pragma unroll
    for (int t = 0; t < 2; ++t) {
      int krow = j0 + 16 * t + cl;
      if (krow > SLEN - 1) krow = SLEN - 1;
      const unsigned short* kp = kb + ((size_t)(b * SLEN + krow) * NKV + kvh) * HD + g * 8;
      bf16x8 kf0 = *(const bf16x8*)kp;
      bf16x8 kf1 = *(const bf16x8*)(kp + 32);
      f32x4 z = {};
      z = __builtin_amdgcn_mfma_f32_16x16x32_bf16(kf0, qf0, z, 0, 0, 0);
      z = __builtin_amdgcn_mfma_f32_16x16x32_bf16(kf1, qf1, z, 0, 0, 0);
      sacc[t] = z;
    }
    float s[2][4];
    float mx = -1e30f;
#pragma unroll
    for (int t = 0; t < 2; ++t)
#pragma unroll
      for (int p = 0; p < 4; ++p) {
        int kj = j0 + 16 * t + g * 4 + p;
        bool ok = (kj <= qi) && (qi - kj <= WINH);
        float v = ok ? sacc[t][p] * 0.125f : -1e30f;
        s[t][p] = v;
        mx = fmaxf(mx, v);
      }
    mx = fmaxf(mx, __shfl_xor(mx, 16));
    mx = fmaxf(mx, __shfl_xor(mx, 32));
    float mnew = fmaxf(m_run, mx);
    float corr = __expf(m_run - mnew);
    float ps = 0.f;
    unsigned pw[2][2];
#pragma unroll
    for (int t = 0; t < 2; ++t) {
      float p0 = __expf(s[t][0] - mnew);
      float p1 = __expf(s[t][1] - mnew);
      float p2 = __expf(s[t][2] - mnew);
      float p3 = __expf(s[t][3] - mnew);
      ps += p0 + p1 + p2 + p3;
      pw[t][0] = pk2(p0, p1);
      pw[t][1] = pk2(p2, p3);
    }
    ps += __shfl_xor(ps, 16);
    ps += __shfl_xor(ps, 32);
    l_run = l_run * corr + ps;
    m_run = mnew;
#pragma unroll
    for (int vbk = 0; vbk < 4; ++vbk)
#pragma unroll
      for (int p = 0; p < 4; ++p) acc_o[vbk][p] *= corr;
#pragma unroll
    for (int t = 0; t < 2; ++t) {
      *(unsigned*)&Plds[wid][cl][16 * t + 4 * g]     = pw[t][0];
      *(unsigned*)&Plds[wid][cl][16 * t + 4 * g + 2] = pw[t][1];
    }
    bf16x8 pf = *(const bf16x8*)&Plds[wid][cl][g * 8];
    int jv = j0 + g * 8;
    if (jv > SLEN - 8) jv = SLEN - 8;
    const unsigned short* vbase = vt + ((size_t)(b * NKV + kvh) * HD) * SLEN + jv;
#pragma unroll
    for (int vbk = 0; vbk < 4; ++vbk) {
      bf16x8 vf = *(const bf16x8*)(vbase + (size_t)(vbk * 16 + cl) * SLEN);
      acc_o[vbk] = __builtin_amdgcn_mfma_f32_16x16x32_bf16(vf, pf, acc_o[vbk], 0, 0, 0);
    }
  }
  float inv = 1.0f / l_run;
  unsigned short* op = ao + ((size_t)(b * SLEN + i0 + cl) * NH + h) * HD;
#pragma unroll
  for (int vbk = 0; vbk < 4; ++vbk) {
    unsigned u0 = pk2(acc_o[vbk][0] * inv, acc_o[vbk][1] * inv);
    unsigned u1 = pk2(acc_o[vbk][2] * inv, acc_o[vbk][3] * inv);
    *(unsigned*)(op + vbk * 16 + g * 4)     = u0;
    *(unsigned*)(op + vbk * 16 + g * 4 + 2) = u1;
  }
}

// ---------------- launch ---------------------------------------------------
extern "C" void kernel_launch(void* const* d_in, const int* in_sizes, int n_in,
                              void* d_out, int out_size, void* d_ws, size_t ws_size,
                              hipStream_t stream) {
  const float* x  = (const float*)d_in[0];
  const float* wq = (const float*)d_in[1];
  const float* wk = (const float*)d_in[2];
  const float* wv = (const float*)d_in[3];
  const float* wo = (const float*)d_in[4];
  float* out = (float*)d_out;

  char* w = (char*)d_ws;
  unsigned short* wqkvb = (unsigned short*)w; w += (size_t)3072 * 2048 * 2;   // 12 MB
  unsigned short* xb    = (unsigned short*)w; w += (size_t)MROWS * QDIM * 2;  // 16 MB
  unsigned short* qb    = (unsigned short*)w; w += (size_t)MROWS * QDIM * 2;  // 16 MB
  unsigned short* kb    = (unsigned short*)w; w += (size_t)MROWS * KVDIM * 2; // 4 MB
  unsigned short* vt    = (unsigned short*)w; w += (size_t)MROWS * KVDIM * 2; // 4 MB
  float* tab            = (float*)w;          w += (size_t)SLEN * 32 * 8;     // 0.5 MB
  // aliases (lifetimes disjoint in stream order):
  unsigned short* wob = wqkvb;   // wo bf16 — written after qkv_gemm reads wqkvb
  unsigned short* ao  = xb;      // attn output — written after qkv_gemm reads xb

  hipFuncSetAttribute((const void*)qkv_gemm,
                      hipFuncAttributeMaxDynamicSharedMemorySize, 131072);
  hipFuncSetAttribute((const void*)out_gemm,
                      hipFuncAttributeMaxDynamicSharedMemorySize, 98304);

  rope_table<<<SLEN * 32 / 256, 256, 0, stream>>>((float2*)tab);
  conv_bf16<<<(MROWS * 2048) / (8 * 256), 256, 0, stream>>>(x, xb);
  conv_wqkv<<<(3072 * 2048) / (8 * 256), 256, 0, stream>>>(wq, wk, wv, wqkvb);
  qkv_gemm<<<192, 512, 131072, stream>>>(xb, wqkvb, tab, qb, kb, vt);
  conv_bf16<<<(2048 * 2048) / (8 * 256), 256, 0, stream>>>(wo, wob);
  attn<<<(NB * NH * (SLEN / 16)) / 4, 256, 0, stream>>>(qb, kb, vt, ao);
  out_gemm<<<256, 512, 98304, stream>>>(ao, wob, out);
}

// Round 5
// 194.692 us; speedup vs baseline: 1.4239x; 1.0409x over previous
//
#include <hip/hip_runtime.h>
#include <cstdint>
#include <cstddef>

#define SLEN 2048
#define NB 2
#define NH 32
#define NKV 8
#define HD 64
#define MROWS 4096   // NB*SLEN
#define QDIM 2048    // NH*HD
#define KVDIM 512    // NKV*HD
#define WINH 256     // WIN/2

typedef float f32x4 __attribute__((ext_vector_type(4)));
typedef __bf16 bf16x8 __attribute__((ext_vector_type(8)));

__device__ __forceinline__ unsigned short f2bf(float f) {
  union { float f; unsigned u; } v; v.f = f;
  unsigned r = v.u + 0x7fffu + ((v.u >> 16) & 1u);
  return (unsigned short)(r >> 16);
}
__device__ __forceinline__ float bf2f(unsigned short h) {
  union { unsigned u; float f; } v; v.u = ((unsigned)h) << 16;
  return v.f;
}
__device__ __forceinline__ unsigned pk2(float a, float b) {
  return (unsigned)f2bf(a) | ((unsigned)f2bf(b) << 16);
}
__device__ __forceinline__ uint4 cvt16(float4 a, float4 b) {
  uint4 u;
  u.x = pk2(a.x, a.y); u.y = pk2(a.z, a.w);
  u.z = pk2(b.x, b.y); u.w = pk2(b.z, b.w);
  return u;
}
// async global->LDS, 16B per lane; LDS dest is wave-uniform base + lane*16
__device__ __forceinline__ void async16(const unsigned short* g, unsigned short* l) {
  __builtin_amdgcn_global_load_lds(
      (const __attribute__((address_space(1))) unsigned int*)g,
      (__attribute__((address_space(3))) unsigned int*)l, 16, 0, 0);
}

// ---------------- RoPE table: tab[s*32+d] = {cos, sin} ---------------------
__global__ void rope_table(float2* __restrict__ tab) {
  int tid = blockIdx.x * 256 + threadIdx.x;      // 2048*32 = 65536
  int d = tid & 31;
  int s = tid >> 5;
  float inv = expf((float)d * (-2.0f / 64.0f) * 9.210340371976184f);
  float ang = (float)s * inv;
  float sn, cs;
  sincosf(ang, &sn, &cs);
  tab[tid] = make_float2(cs, sn);
}

// ---------------- fp32 -> bf16 converters ----------------------------------
__global__ void conv_bf16(const float* __restrict__ src, unsigned short* __restrict__ dst) {
  size_t t = (size_t)blockIdx.x * 256 + threadIdx.x;
  float4 a = *(const float4*)(src + t * 8);
  float4 b = *(const float4*)(src + t * 8 + 4);
  *(uint4*)(dst + t * 8) = cvt16(a, b);
}

__global__ void conv_wqkv(const float* __restrict__ wq, const float* __restrict__ wk,
                          const float* __restrict__ wv, unsigned short* __restrict__ dst) {
  size_t t = (size_t)blockIdx.x * 256 + threadIdx.x;   // 786432 threads
  size_t e = t * 8;
  int row = (int)(e >> 11);
  const float* src; size_t off;
  if (row < 2048)       { src = wq; off = e; }
  else if (row < 2560)  { src = wk; off = e - (size_t)2048 * 2048; }
  else                  { src = wv; off = e - (size_t)2560 * 2048; }
  float4 a = *(const float4*)(src + off);
  float4 b = *(const float4*)(src + off + 4);
  *(uint4*)(dst + e) = cvt16(a, b);
}

// ======================= QKV GEMM: 256x256, 8-wave, 2-barrier/tile =========
// BM=BN=256, BK=64, per-wave 128x64. 128 KiB LDS, counted vmcnt.
// Per tile: 4 MFMA blocks (mh x kh), frags register-pipelined across blocks;
// barriers only at mid-tile (before k0(t+2) overwrite) and tile end (publish).
__global__ __launch_bounds__(512, 2) void qkv_gemm(
    const unsigned short* __restrict__ Ap, const unsigned short* __restrict__ Bp,
    const float* __restrict__ tabf,
    unsigned short* __restrict__ o_q, unsigned short* __restrict__ o_k,
    unsigned short* __restrict__ o_v)
{
  extern __shared__ unsigned short L[];
  constexpr int NT = 32;             // K = 2048 / 64

  const int bid = blockIdx.x;        // 192 blocks (16 x 12), 192 % 8 == 0
  const int swz = (bid & 7) * 24 + (bid >> 3);
  const int bm0 = (swz & 15) * 256;
  const int bn0 = (swz >> 4) * 256;

  const int tid = threadIdx.x;
  const int lane = tid & 63, wid = tid >> 6;
  const int g = lane >> 4, cl = lane & 15;
  const int wm = wid >> 2, wn = wid & 3;

  // staging geometry: rows wid*32..+31, pre-swizzled global k-slot
  const int r0 = wid * 32 + (lane >> 2);
  const int s0 = (((lane & 3) ^ ((lane >> 3) & 3)) << 3);
  const unsigned short* gA = Ap + (size_t)(bm0 + r0) * 2048 + s0;
  const unsigned short* gB = Bp + (size_t)(bn0 + r0) * 2048 + s0;

  // read geometry; k-slot swizzled by (row>>1)&3 = (cl>>1)&3
  const int slotus = ((g ^ ((cl >> 1) & 3)) << 3);
  const int aread = (wm * 128 + cl) * 32 + slotus;
  const int bread = (wn * 64 + cl) * 32 + slotus;

#define REG_(b, op, kh) ((((b) * 2 + (op)) * 2 + (kh)) * 8192)
#define STG(op, kh, tt, db) do { \
    const unsigned short* s_ = ((op) ? gB : gA) + (tt) * 64 + (kh) * 32; \
    unsigned short* d_ = L + REG_(db, op, kh) + wid * 1024; \
    async16(s_, d_); \
    async16(s_ + 16 * 2048, d_ + 512); \
  } while (0)
#define LDA(dst, kh, mh) \
    _Pragma("unroll") for (int mf = 0; mf < 4; ++mf) \
      dst[mf] = *(const bf16x8*)&L[REG_(cb, 0, kh) + aread + (mh) * 2048 + mf * 512];
#define LDB(dst, kh) \
    _Pragma("unroll") for (int nf = 0; nf < 4; ++nf) \
      dst[nf] = *(const bf16x8*)&L[REG_(cb, 1, kh) + bread + nf * 512];
#define MM(mh, A, B) do { \
    __builtin_amdgcn_s_setprio(1); \
    _Pragma("unroll") for (int mf = 0; mf < 4; ++mf) \
      _Pragma("unroll") for (int nf = 0; nf < 4; ++nf) \
        acc[(mh) * 4 + mf][nf] = __builtin_amdgcn_mfma_f32_16x16x32_bf16( \
            A[mf], B[nf], acc[(mh) * 4 + mf][nf], 0, 0, 0); \
    __builtin_amdgcn_s_setprio(0); \
  } while (0)

  f32x4 acc[8][4] = {};

  // prologue: tile0 fully + tile1 k0; vmcnt(4) -> tile0 resident
  STG(0, 0, 0, 0); STG(1, 0, 0, 0); STG(0, 1, 0, 0); STG(1, 1, 0, 0);
  STG(0, 0, 1, 1); STG(1, 0, 1, 1);
  asm volatile("s_waitcnt vmcnt(4)" ::: "memory");
  __builtin_amdgcn_s_barrier();
  __builtin_amdgcn_sched_barrier(0);

#pragma unroll 1
  for (int t = 0; t < NT; ++t) {
    const int cb = t & 1, nb = cb ^ 1;
    bf16x8 a00[4], a10[4], a01[4], a11[4], b0[4], b1[4];

    if (t + 1 < NT) STG(0, 1, t + 1, nb);       // A-k1(t+1) -> nb
    LDA(a00, 0, 0); LDB(b0, 0);
    if (t + 1 < NT) STG(1, 1, t + 1, nb);       // B-k1(t+1) -> nb
    LDA(a10, 0, 1);
    MM(0, a00, b0);                             // overlaps a10/a01/b1 reads
    LDA(a01, 1, 0); LDB(b1, 1);
    MM(1, a10, b0);                             // last kh0 consumer
    asm volatile("s_waitcnt lgkmcnt(0)" ::: "memory");
    __builtin_amdgcn_s_barrier();               // mid: k0(cb) free to overwrite
    __builtin_amdgcn_sched_barrier(0);
    if (t + 2 < NT) STG(0, 0, t + 2, cb);       // A-k0(t+2) -> cb
    LDA(a11, 1, 1);
    MM(0, a01, b1);
    if (t + 2 < NT) STG(1, 0, t + 2, cb);       // B-k0(t+2) -> cb
    MM(1, a11, b1);
    if (t + 2 < NT) { asm volatile("s_waitcnt vmcnt(4)" ::: "memory"); }
    else            { asm volatile("s_waitcnt vmcnt(0)" ::: "memory"); }
    asm volatile("s_waitcnt lgkmcnt(0)" ::: "memory");
    __builtin_amdgcn_s_barrier();               // end: tile t+1 published
    __builtin_amdgcn_sched_barrier(0);
  }
#undef MM
#undef LDB
#undef LDA
#undef STG
#undef REG_

  // ---------------- epilogue: fused RoPE (q,k) / transposed V write --------
  const int rb = bm0 + wm * 128;
  const float2* tab = (const float2*)tabf;
  if (bn0 < QDIM) {
    const int colb = bn0 + wn * 64;       // head*64
#pragma unroll
    for (int m = 0; m < 8; ++m)
#pragma unroll
      for (int nf = 0; nf < 2; ++nf) {
        const int d = nf * 16 + cl;
#pragma unroll
        for (int p = 0; p < 4; ++p) {
          int row = rb + m * 16 + g * 4 + p;
          int s = row & (SLEN - 1);
          float2 cs = tab[s * 32 + d];
          float a = acc[m][nf][p], b2 = acc[m][nf + 2][p];
          o_q[(size_t)row * QDIM + colb + d]      = f2bf(a * cs.x - b2 * cs.y);
          o_q[(size_t)row * QDIM + colb + d + 32] = f2bf(b2 * cs.x + a * cs.y);
        }
      }
  } else if (bn0 < QDIM + KVDIM) {
    const int colb = bn0 - QDIM + wn * 64;
#pragma unroll
    for (int m = 0; m < 8; ++m)
#pragma unroll
      for (int nf = 0; nf < 2; ++nf) {
        const int d = nf * 16 + cl;
#pragma unroll
        for (int p = 0; p < 4; ++p) {
          int row = rb + m * 16 + g * 4 + p;
          int s = row & (SLEN - 1);
          float2 cs = tab[s * 32 + d];
          float a = acc[m][nf][p], b2 = acc[m][nf + 2][p];
          o_k[(size_t)row * KVDIM + colb + d]      = f2bf(a * cs.x - b2 * cs.y);
          o_k[(size_t)row * KVDIM + colb + d + 32] = f2bf(b2 * cs.x + a * cs.y);
        }
      }
  } else {
    const int colb = bn0 - QDIM - KVDIM + wn * 64;
#pragma unroll
    for (int m = 0; m < 8; ++m)
#pragma unroll
      for (int nf = 0; nf < 4; ++nf) {
        int col = colb + nf * 16 + cl;          // kvh*64 + d
        int kvh = col >> 6, d = col & 63;
        int row0 = rb + m * 16 + g * 4;
        int bb = row0 >> 11, s = row0 & (SLEN - 1);
        unsigned short* dst = o_v + (((size_t)(bb * NKV + kvh) * HD + d) << 11) + s;
        uint2 u;
        u.x = pk2(acc[m][nf][0], acc[m][nf][1]);
        u.y = pk2(acc[m][nf][2], acc[m][nf][3]);
        *(uint2*)dst = u;
      }
  }
}

// ======================= OUT GEMM: 128x256, 8-wave, 2-barrier/tile =========
// BM=128, BN=256 -> grid 32x8 = 256 blocks (all CUs). Per-wave 64x64.
// LDS 96 KiB: per buf {A:4096, B-k0:8192(off 8192), B-k1:8192} ushorts.
__global__ __launch_bounds__(512, 2) void out_gemm(
    const unsigned short* __restrict__ Ap, const unsigned short* __restrict__ Bp,
    float* __restrict__ o_f)
{
  extern __shared__ unsigned short L[];
  constexpr int NT = 32;

  const int bid = blockIdx.x;        // 256 blocks (32 x 8)
  const int swz = (bid & 7) * 32 + (bid >> 3);
  const int bm0 = (swz & 31) * 128;
  const int bn0 = (swz >> 5) * 256;

  const int tid = threadIdx.x;
  const int lane = tid & 63, wid = tid >> 6;
  const int g = lane >> 4, cl = lane & 15;
  const int wm = wid >> 2, wn = wid & 3;

  const int s0 = (((lane & 3) ^ ((lane >> 3) & 3)) << 3);
  const unsigned short* gA = Ap + (size_t)(bm0 + wid * 16 + (lane >> 2)) * 2048 + s0;
  const unsigned short* gB = Bp + (size_t)(bn0 + wid * 32 + (lane >> 2)) * 2048 + s0;

  const int slotus = ((g ^ ((cl >> 1) & 3)) << 3);
  const int aread = (wm * 64 + cl) * 32 + slotus;
  const int bread = (wn * 64 + cl) * 32 + slotus;

#define REGA_(b, kh) ((b) * 24576 + (kh) * 4096)
#define REGB_(b, kh) ((b) * 24576 + 8192 + (kh) * 8192)
#define STGA(kh, tt, db) \
    async16(gA + (tt) * 64 + (kh) * 32, L + REGA_(db, kh) + wid * 512)
#define STGB(kh, tt, db) do { \
    const unsigned short* s_ = gB + (tt) * 64 + (kh) * 32; \
    unsigned short* d_ = L + REGB_(db, kh) + wid * 1024; \
    async16(s_, d_); \
    async16(s_ + 16 * 2048, d_ + 512); \
  } while (0)
#define LA(dst, kh, mp) \
    _Pragma("unroll") for (int mf = 0; mf < 2; ++mf) \
      dst[mf] = *(const bf16x8*)&L[REGA_(cb, kh) + aread + (mp) * 1024 + mf * 512];
#define LB(dst, kh) \
    _Pragma("unroll") for (int nf = 0; nf < 4; ++nf) \
      dst[nf] = *(const bf16x8*)&L[REGB_(cb, kh) + bread + nf * 512];
#define MMO(mp, A, B) do { \
    __builtin_amdgcn_s_setprio(1); \
    _Pragma("unroll") for (int mf = 0; mf < 2; ++mf) \
      _Pragma("unroll") for (int nf = 0; nf < 4; ++nf) \
        acc[(mp) * 2 + mf][nf] = __builtin_amdgcn_mfma_f32_16x16x32_bf16( \
            A[mf], B[nf], acc[(mp) * 2 + mf][nf], 0, 0, 0); \
    __builtin_amdgcn_s_setprio(0); \
  } while (0)

  f32x4 acc[4][4] = {};

  // prologue: tile0 (6 loads) + tile1-k0 (3 loads); vmcnt(3) -> tile0 resident
  STGA(0, 0, 0); STGB(0, 0, 0); STGA(1, 0, 0); STGB(1, 0, 0);
  STGA(0, 1, 1); STGB(0, 1, 1);
  asm volatile("s_waitcnt vmcnt(3)" ::: "memory");
  __builtin_amdgcn_s_barrier();
  __builtin_amdgcn_sched_barrier(0);

#pragma unroll 1
  for (int t = 0; t < NT; ++t) {
    const int cb = t & 1, nb = cb ^ 1;
    bf16x8 p00[2], p10[2], p01[2], p11[2], b0[4], b1[4];

    if (t + 1 < NT) STGA(1, t + 1, nb);
    LA(p00, 0, 0); LB(b0, 0);
    if (t + 1 < NT) STGB(1, t + 1, nb);
    LA(p10, 0, 1);
    MMO(0, p00, b0);
    LA(p01, 1, 0); LB(b1, 1);
    MMO(1, p10, b0);
    asm volatile("s_waitcnt lgkmcnt(0)" ::: "memory");
    __builtin_amdgcn_s_barrier();
    __builtin_amdgcn_sched_barrier(0);
    if (t + 2 < NT) STGA(0, t + 2, cb);
    LA(p11, 1, 1);
    MMO(0, p01, b1);
    if (t + 2 < NT) STGB(0, t + 2, cb);
    MMO(1, p11, b1);
    if (t + 2 < NT) { asm volatile("s_waitcnt vmcnt(3)" ::: "memory"); }
    else            { asm volatile("s_waitcnt vmcnt(0)" ::: "memory"); }
    asm volatile("s_waitcnt lgkmcnt(0)" ::: "memory");
    __builtin_amdgcn_s_barrier();
    __builtin_amdgcn_sched_barrier(0);
  }
#undef MMO
#undef LB
#undef LA
#undef STGB
#undef STGA
#undef REGB_
#undef REGA_

  const int rb = bm0 + wm * 64;
  const int colb = bn0 + wn * 64;
#pragma unroll
  for (int m = 0; m < 4; ++m)
#pragma unroll
    for (int nf = 0; nf < 4; ++nf)
#pragma unroll
      for (int p = 0; p < 4; ++p) {
        int row = rb + m * 16 + g * 4 + p;
        o_f[(size_t)row * 2048 + colb + nf * 16 + cl] = acc[m][nf][p];
      }
}

// ---------------- Flash attention, sliding window --------------------------
__global__ __launch_bounds__(256) void attn(
    const unsigned short* __restrict__ qb, const unsigned short* __restrict__ kb,
    const unsigned short* __restrict__ vt, unsigned short* __restrict__ ao)
{
  __shared__ __align__(16) unsigned short Plds[4][16][40];
  const int lane = threadIdx.x & 63, wid = threadIdx.x >> 6;
  const int g = lane >> 4, cl = lane & 15;
  const int qt = blockIdx.x * 4 + wid;         // 0..8191
  const int bh = qt >> 7, tl = qt & 127;
  const int i0 = tl * 16;
  const int b = bh >> 5, h = bh & 31, kvh = (bh & 31) >> 2;
  const int qi = i0 + cl;

  const unsigned short* qp = qb + ((size_t)(b * SLEN + i0 + cl) * NH + h) * HD + g * 8;
  bf16x8 qf0 = *(const bf16x8*)qp;
  bf16x8 qf1 = *(const bf16x8*)(qp + 32);

  f32x4 acc_o[4] = {};
  float m_run = -1e30f, l_run = 0.f;
  int jb = i0 - WINH; if (jb < 0) jb = 0;

  for (int j0 = jb; j0 <= i0; j0 += 32) {
    f32x4 sacc[2];
#pragma unroll
    for (int t = 0; t < 2; ++t) {
      int krow = j0 + 16 * t + cl;
      if (krow > SLEN - 1) krow = SLEN - 1;
      const unsigned short* kp = kb + ((size_t)(b * SLEN + krow) * NKV + kvh) * HD + g * 8;
      bf16x8 kf0 = *(const bf16x8*)kp;
      bf16x8 kf1 = *(const bf16x8*)(kp + 32);
      f32x4 z = {};
      z = __builtin_amdgcn_mfma_f32_16x16x32_bf16(kf0, qf0, z, 0, 0, 0);
      z = __builtin_amdgcn_mfma_f32_16x16x32_bf16(kf1, qf1, z, 0, 0, 0);
      sacc[t] = z;
    }
    float s[2][4];
    float mx = -1e30f;
#pragma unroll
    for (int t = 0; t < 2; ++t)
#pragma unroll
      for (int p = 0; p < 4; ++p) {
        int kj = j0 + 16 * t + g * 4 + p;
        bool ok = (kj <= qi) && (qi - kj <= WINH);
        float v = ok ? sacc[t][p] * 0.125f : -1e30f;
        s[t][p] = v;
        mx = fmaxf(mx, v);
      }
    mx = fmaxf(mx, __shfl_xor(mx, 16));
    mx = fmaxf(mx, __shfl_xor(mx, 32));
    float mnew = fmaxf(m_run, mx);
    float corr = __expf(m_run - mnew);
    float ps = 0.f;
    unsigned pw[2][2];
#pragma unroll
    for (int t = 0; t < 2; ++t) {
      float p0 = __expf(s[t][0] - mnew);
      float p1 = __expf(s[t][1] - mnew);
      float p2 = __expf(s[t][2] - mnew);
      float p3 = __expf(s[t][3] - mnew);
      ps += p0 + p1 + p2 + p3;
      pw[t][0] = pk2(p0, p1);
      pw[t][1] = pk2(p2, p3);
    }
    ps += __shfl_xor(ps, 16);
    ps += __shfl_xor(ps, 32);
    l_run = l_run * corr + ps;
    m_run = mnew;
#pragma unroll
    for (int vbk = 0; vbk < 4; ++vbk)
#pragma unroll
      for (int p = 0; p < 4; ++p) acc_o[vbk][p] *= corr;
#pragma unroll
    for (int t = 0; t < 2; ++t) {
      *(unsigned*)&Plds[wid][cl][16 * t + 4 * g]     = pw[t][0];
      *(unsigned*)&Plds[wid][cl][16 * t + 4 * g + 2] = pw[t][1];
    }
    bf16x8 pf = *(const bf16x8*)&Plds[wid][cl][g * 8];
    int jv = j0 + g * 8;
    if (jv > SLEN - 8) jv = SLEN - 8;
    const unsigned short* vbase = vt + ((size_t)(b * NKV + kvh) * HD) * SLEN + jv;
#pragma unroll
    for (int vbk = 0; vbk < 4; ++vbk) {
      bf16x8 vf = *(const bf16x8*)(vbase + (size_t)(vbk * 16 + cl) * SLEN);
      acc_o[vbk] = __builtin_amdgcn_mfma_f32_16x16x32_bf16(vf, pf, acc_o[vbk], 0, 0, 0);
    }
  }
  float inv = 1.0f / l_run;
  unsigned short* op = ao + ((size_t)(b * SLEN + i0 + cl) * NH + h) * HD;
#pragma unroll
  for (int vbk = 0; vbk < 4; ++vbk) {
    unsigned u0 = pk2(acc_o[vbk][0] * inv, acc_o[vbk][1] * inv);
    unsigned u1 = pk2(acc_o[vbk][2] * inv, acc_o[vbk][3] * inv);
    *(unsigned*)(op + vbk * 16 + g * 4)     = u0;
    *(unsigned*)(op + vbk * 16 + g * 4 + 2) = u1;
  }
}

// ---------------- launch ---------------------------------------------------
extern "C" void kernel_launch(void* const* d_in, const int* in_sizes, int n_in,
                              void* d_out, int out_size, void* d_ws, size_t ws_size,
                              hipStream_t stream) {
  const float* x  = (const float*)d_in[0];
  const float* wq = (const float*)d_in[1];
  const float* wk = (const float*)d_in[2];
  const float* wv = (const float*)d_in[3];
  const float* wo = (const float*)d_in[4];
  float* out = (float*)d_out;

  char* w = (char*)d_ws;
  unsigned short* wqkvb = (unsigned short*)w; w += (size_t)3072 * 2048 * 2;   // 12 MB
  unsigned short* xb    = (unsigned short*)w; w += (size_t)MROWS * QDIM * 2;  // 16 MB
  unsigned short* qb    = (unsigned short*)w; w += (size_t)MROWS * QDIM * 2;  // 16 MB
  unsigned short* kb    = (unsigned short*)w; w += (size_t)MROWS * KVDIM * 2; // 4 MB
  unsigned short* vt    = (unsigned short*)w; w += (size_t)MROWS * KVDIM * 2; // 4 MB
  float* tab            = (float*)w;          w += (size_t)SLEN * 32 * 8;     // 0.5 MB
  // aliases (lifetimes disjoint in stream order):
  unsigned short* wob = wqkvb;   // wo bf16 — written after qkv_gemm reads wqkvb
  unsigned short* ao  = xb;      // attn output — written after qkv_gemm reads xb

  hipFuncSetAttribute((const void*)qkv_gemm,
                      hipFuncAttributeMaxDynamicSharedMemorySize, 131072);
  hipFuncSetAttribute((const void*)out_gemm,
                      hipFuncAttributeMaxDynamicSharedMemorySize, 98304);

  rope_table<<<SLEN * 32 / 256, 256, 0, stream>>>((float2*)tab);
  conv_bf16<<<(MROWS * 2048) / (8 * 256), 256, 0, stream>>>(x, xb);
  conv_wqkv<<<(3072 * 2048) / (8 * 256), 256, 0, stream>>>(wq, wk, wv, wqkvb);
  qkv_gemm<<<192, 512, 131072, stream>>>(xb, wqkvb, tab, qb, kb, vt);
  conv_bf16<<<(2048 * 2048) / (8 * 256), 256, 0, stream>>>(wo, wob);
  attn<<<(NB * NH * (SLEN / 16)) / 4, 256, 0, stream>>>(qb, kb, vt, ao);
  out_gemm<<<256, 512, 98304, stream>>>(ao, wob, out);
}